// Round 16
// baseline (342.026 us; speedup 1.0000x reference)
//
#include <hip/hip_runtime.h>
#include <hip/hip_bf16.h>
#include <hip/hip_fp16.h>
#include <math.h>

#define HSZ 192
#define WSZ 192
#define HWSZ (192*192)
#define PH 194                 // padded dim
#define PP (PH*PH)             // 37636 padded pixels
#define NB 4

typedef __attribute__((ext_vector_type(8))) short short8;
typedef __attribute__((ext_vector_type(4))) float f32x4;

__device__ inline unsigned short f2bf(float f) { __hip_bfloat16 h = __float2bfloat16(f); return *(unsigned short*)&h; }
__device__ inline float bf2f(__hip_bfloat16 h) { return __bfloat162float(h); }
__device__ inline float bflo(unsigned u) { return __uint_as_float(u << 16); }
__device__ inline float bfhi(unsigned u) { return __uint_as_float(u & 0xffff0000u); }

#define GLDS(SRC, DST) __builtin_amdgcn_global_load_lds( \
    (const __attribute__((address_space(1))) unsigned int*)(const void*)(SRC), \
    (__attribute__((address_space(3))) unsigned int*)(void*)(DST), 16, 0, 0)

#define MFMA(A,B,C) __builtin_amdgcn_mfma_f32_16x16x32_bf16((A),(B),(C),0,0,0)

// ------------- merged border-zero (4 buffers) -------------
__global__ void zb2_k(__hip_bfloat16* xn, __hip_bfloat16* r1, __hip_bfloat16* res,
                      __hip_bfloat16* cat) {
  int job = blockIdx.y;
  __hip_bfloat16* buf = job == 0 ? xn : job == 1 ? r1 : job == 2 ? res : cat;
  int Cn = (job == 3) ? 128 : 64;
  int cg8 = Cn >> 3;
  int tot = NB * 772 * cg8;
  int idx = blockIdx.x * 256 + threadIdx.x;
  if (idx >= tot) return;
  int cg = idx % cg8; int rem = idx / cg8;
  int e = rem % 772; int b = rem / 772;
  int h, w2;
  if (e < 194) { h = 0; w2 = e; }
  else if (e < 388) { h = 193; w2 = e - 194; }
  else if (e < 580) { h = e - 388 + 1; w2 = 0; }
  else { h = e - 580 + 1; w2 = 193; }
  uint4 z = make_uint4(0, 0, 0, 0);
  *(uint4*)&buf[(((size_t)b * PH + h) * PH + w2) * Cn + cg * 8] = z;
}

// ------------- merged weight prep (5 jobs) + mean zero -------------
__global__ void wts_k(const float* __restrict__ rw1, const float* __restrict__ rw2,
                      const float* __restrict__ cw, const float* __restrict__ offw,
                      const float* __restrict__ maskw, const float* __restrict__ offb,
                      const float* __restrict__ maskb, const float* __restrict__ dwv,
                      short* wt1, short* wt2c, short* wtf, short* wtom, float* ob,
                      short* wtb, float* meanz) {
  int job = blockIdx.y;
  int idx = blockIdx.x * 256 + threadIdx.x;   // < 36864
  if (job < 3) {
    const float* src = job == 0 ? rw1 : job == 1 ? rw2 : cw;
    short* dst = job == 0 ? wt1 : job == 1 ? wt2c : wtf;
    int kk = idx >> 12, rem = idx & 4095;
    int co = rem >> 6, ci = rem & 63;
    dst[idx] = (short)f2bf(src[(co * 64 + ci) * 9 + kk]);
  } else if (job == 3) {
    int kk = idx >> 12, rem = idx & 4095;
    int co = rem >> 7, ci = rem & 127;
    float v = 0.f;
    if (co < 18) v = offw[(co * 128 + ci) * 9 + kk];
    else if (co < 27) v = maskw[((co - 18) * 128 + ci) * 9 + kk];
    wtom[idx] = (short)f2bf(v);
    if (idx < 32) ob[idx] = idx < 18 ? offb[idx] : (idx < 27 ? maskb[idx - 18] : 0.f);
  } else {
    int o = idx / 576, rem = idx - o * 576;
    int kk = rem >> 6, ci = rem & 63;
    wtb[idx] = (short)f2bf(dwv[(o * 64 + ci) * 9 + kk]);
    if (blockIdx.x == 0 && threadIdx.x < 256) meanz[threadIdx.x] = 0.f;
  }
}

// ------------- merged NCHW f32 -> padded NHWC bf16 (x -> xn, inter/fea -> cat) -------------
__global__ __launch_bounds__(256) void cvt_k(const float* __restrict__ x,
    const float* __restrict__ inter, const float* __restrict__ fea,
    __hip_bfloat16* __restrict__ xn, __hip_bfloat16* __restrict__ cat) {
  int job = blockIdx.z;
  const float* src = job == 0 ? x : job == 1 ? inter : fea;
  __hip_bfloat16* dst = job == 0 ? xn : cat;
  int Cdst = job == 0 ? 64 : 128;
  int coff = job == 2 ? 64 : 0;
  __shared__ float s[64][65];
  int p0 = blockIdx.x * 64; int b = blockIdx.y;
  int lane = threadIdx.x & 63, g = threadIdx.x >> 6;
#pragma unroll
  for (int i = 0; i < 16; ++i) {
    int c = i * 4 + g;
    s[c][lane] = src[((size_t)b * 64 + c) * HWSZ + p0 + lane];
  }
  __syncthreads();
  int pix = threadIdx.x >> 2, cg = threadIdx.x & 3;
  int h = p0 / WSZ, w0 = p0 - h * WSZ + pix;
  size_t addr = (((size_t)b * PH + h + 1) * PH + 1 + w0) * Cdst + coff + cg * 16;
  unsigned pk2[8];
#pragma unroll
  for (int t = 0; t < 8; ++t)
    pk2[t] = (unsigned)f2bf(s[cg * 16 + 2 * t][pix]) | ((unsigned)f2bf(s[cg * 16 + 2 * t + 1][pix]) << 16);
  *(uint4*)&dst[addr]     = make_uint4(pk2[0], pk2[1], pk2[2], pk2[3]);
  *(uint4*)&dst[addr + 8] = make_uint4(pk2[4], pk2[5], pk2[6], pk2[7]);
}

// ------------- conv3x3 body (row-dbuf, validated R13/R14); tbuf = 2 x 12800 shorts -------------
template<int OUT_MODE, bool RELU, bool MEANACC>
__device__ __forceinline__ void conv_body(int vbid, short* tbuf, float* smean,
    const __hip_bfloat16* __restrict__ inp, const short* __restrict__ wt,
    const float* __restrict__ bias, __hip_bfloat16* __restrict__ outB,
    float* __restrict__ outF, float* __restrict__ meanout) {
  int flat = (vbid & 7) * 96 + (vbid >> 3);
  const int b = flat / 192, h = flat - (flat / 192) * 192;
  const int tid = threadIdx.x, lane = tid & 63, wid = tid >> 6;
  const int q = lane >> 4, r16 = lane & 15;

  const __hip_bfloat16* base = inp + ((size_t)b * PH + h) * (PH * 64);
#define STAGE(BUF, R) do { \
    const char* gb_ = (const char*)(base + (size_t)(R) * (PH * 64)); \
    for (int s_ = wid; s_ < 25; s_ += 4) { \
      int pix_ = 8 * s_ + (lane >> 3); \
      const char* src_ = gb_ + pix_ * 128 + ((((lane & 7) ^ ((lane >> 3) & 7))) << 4); \
      GLDS(src_, tbuf + (BUF) * 12800 + s_ * 512); \
    } \
  } while (0)

  STAGE(0, 0);

  f32x4 acc[3][4];
  if (OUT_MODE == 0) {
#pragma unroll
    for (int nf = 0; nf < 4; ++nf) {
      float4 bv = *(const float4*)&bias[nf * 16 + q * 4];
      f32x4 v; v[0] = bv.x; v[1] = bv.y; v[2] = bv.z; v[3] = bv.w;
      acc[0][nf] = v; acc[1][nf] = v; acc[2][nf] = v;
    }
  } else {
#pragma unroll
    for (int nf = 0; nf < 4; ++nf) {
      float bs = bias[nf * 16 + r16];
      f32x4 v; v[0] = bs; v[1] = bs; v[2] = bs; v[3] = bs;
      acc[0][nf] = v; acc[1][nf] = v; acc[2][nf] = v;
    }
  }

  short8 bfr[2][2][4];
  {
    const short* wk0 = wt + r16 * 64 + q * 8;
#pragma unroll
    for (int nf = 0; nf < 4; ++nf) {
      bfr[0][0][nf] = *(const short8*)(wk0 + nf * 1024);
      bfr[0][1][nf] = *(const short8*)(wk0 + nf * 1024 + 32);
    }
  }
  __syncthreads();

  const int wm0 = wid * 48;
#pragma unroll
  for (int ky = 0; ky < 3; ++ky) {
    const int cb = ky & 1;
    if (ky < 2) STAGE(cb ^ 1, ky + 1);
#pragma unroll
    for (int kx = 0; kx < 3; ++kx) {
      const int kk = ky * 3 + kx;
      const int cur = kk & 1;
      if (kk < 8) {
        const short* wk = wt + (kk + 1) * 4096 + r16 * 64 + q * 8;
#pragma unroll
        for (int nf = 0; nf < 4; ++nf) {
          bfr[cur ^ 1][0][nf] = *(const short8*)(wk + nf * 1024);
          bfr[cur ^ 1][1][nf] = *(const short8*)(wk + nf * 1024 + 32);
        }
      }
#pragma unroll
      for (int mf = 0; mf < 3; ++mf) {
        int pix = wm0 + mf * 16 + r16 + kx;
        const char* ab = (const char*)(tbuf + cb * 12800) + pix * 128;
        int sw = (pix & 7) << 4;
        short8 a0 = *(const short8*)(ab + ((q << 4) ^ sw));
        short8 a1 = *(const short8*)(ab + (((q + 4) << 4) ^ sw));
#pragma unroll
        for (int nf = 0; nf < 4; ++nf) {
          if (OUT_MODE == 0) {
            acc[mf][nf] = MFMA(bfr[cur][0][nf], a0, acc[mf][nf]);
            acc[mf][nf] = MFMA(bfr[cur][1][nf], a1, acc[mf][nf]);
          } else {
            acc[mf][nf] = MFMA(a0, bfr[cur][0][nf], acc[mf][nf]);
            acc[mf][nf] = MFMA(a1, bfr[cur][1][nf], acc[mf][nf]);
          }
        }
      }
    }
    __syncthreads();
  }
#undef STAGE

  if (MEANACC) {
    float t[4][4];
#pragma unroll
    for (int nf = 0; nf < 4; ++nf)
#pragma unroll
      for (int rg = 0; rg < 4; ++rg)
        t[nf][rg] = acc[0][nf][rg] + acc[1][nf][rg] + acc[2][nf][rg];
#pragma unroll
    for (int m = 1; m < 16; m <<= 1)
#pragma unroll
      for (int nf = 0; nf < 4; ++nf)
#pragma unroll
        for (int rg = 0; rg < 4; ++rg)
          t[nf][rg] += __shfl_xor(t[nf][rg], m);
    if (r16 == 0)
#pragma unroll
      for (int nf = 0; nf < 4; ++nf)
#pragma unroll
        for (int rg = 0; rg < 4; ++rg)
          smean[wid * 64 + nf * 16 + q * 4 + rg] = t[nf][rg];
    __syncthreads();
    if (tid < 64)
      atomicAdd(&meanout[b * 64 + tid],
                (smean[tid] + smean[64 + tid] + smean[128 + tid] + smean[192 + tid]) * (1.f / 36864.f));
  }

  if (OUT_MODE == 0) {
    short* t1 = tbuf + 12800;
#pragma unroll
    for (int mf = 0; mf < 3; ++mf)
#pragma unroll
      for (int nf = 0; nf < 4; ++nf) {
        f32x4 v = acc[mf][nf];
        if (RELU) { v[0] = fmaxf(v[0], 0.f); v[1] = fmaxf(v[1], 0.f); v[2] = fmaxf(v[2], 0.f); v[3] = fmaxf(v[3], 0.f); }
        unsigned lo = (unsigned)f2bf(v[0]) | ((unsigned)f2bf(v[1]) << 16);
        unsigned hi = (unsigned)f2bf(v[2]) | ((unsigned)f2bf(v[3]) << 16);
        int pix = wm0 + mf * 16 + r16;
        int byteoff = (pix * 128 + nf * 32 + q * 8) ^ ((pix & 7) << 4);
        *(uint2*)((char*)t1 + byteoff) = make_uint2(lo, hi);
      }
    __syncthreads();
    char* orow = (char*)outB + ((((size_t)b * PH + h + 1) * PH + 1) * 64) * 2;
    for (int s = wid; s < 24; s += 4) {
      int pix = 8 * s + (lane >> 3);
      int g16 = ((lane & 7) ^ (pix & 7)) << 4;
      uint4 d = *(const uint4*)((const char*)t1 + pix * 128 + g16);
      *(uint4*)(orow + pix * 128 + ((lane & 7) << 4)) = d;
    }
  } else {
    float* ob2 = outF + (size_t)b * 64 * HWSZ + h * WSZ;
#pragma unroll
    for (int mf = 0; mf < 3; ++mf)
#pragma unroll
      for (int nf = 0; nf < 4; ++nf) {
        int pix0 = wm0 + mf * 16 + q * 4;
        int co = nf * 16 + r16;
        *(f32x4*)&ob2[(size_t)co * HWSZ + pix0] = acc[mf][nf];
      }
  }
}

// ------------- offmask body (R14); tbuf = 25600 shorts -------------
__device__ __forceinline__ void offmask_body(int vbid, short* tbuf,
    const __hip_bfloat16* __restrict__ cat, const short* __restrict__ wt2,
    const float* __restrict__ ob, float* __restrict__ om) {
  int flat = (vbid & 7) * 96 + (vbid >> 3);
  const int b = flat / 192, h = flat - (flat / 192) * 192;
  const int tid = threadIdx.x, lane = tid & 63, wid = tid >> 6;
  const int q = lane >> 4, r16 = lane & 15;

  f32x4 acc[3][2];
#pragma unroll
  for (int nf = 0; nf < 2; ++nf) {
    float bs = ob[nf * 16 + r16];
    f32x4 v; v[0] = bs; v[1] = bs; v[2] = bs; v[3] = bs;
    acc[0][nf] = v; acc[1][nf] = v; acc[2][nf] = v;
  }
  const char* gb = (const char*)(cat + ((size_t)b * PH + h) * (PH * 128));
  const int wm0 = wid * 48;

  short8 bfr[2][4][2];
  {
    const short* wk0 = wt2 + r16 * 128 + q * 8;
#pragma unroll
    for (int c4 = 0; c4 < 4; ++c4) {
      bfr[0][c4][0] = *(const short8*)(wk0 + c4 * 32);
      bfr[0][c4][1] = *(const short8*)(wk0 + 2048 + c4 * 32);
    }
  }

#pragma unroll
  for (int r = 0; r < 3; ++r) {
    __syncthreads();
    for (int s = wid; s < 50; s += 4) {
      int pix = 4 * s + (lane >> 4);
      const char* src = gb + (size_t)r * (PH * 256) + pix * 256
                      + ((((lane & 15) ^ (pix & 15))) << 4);
      GLDS(src, tbuf + s * 512);
    }
    __syncthreads();
#pragma unroll
    for (int kx = 0; kx < 3; ++kx) {
      const int kk = r * 3 + kx;
      const int cur = kk & 1;
      if (kk < 8) {
        const short* wk = wt2 + (kk + 1) * 4096 + r16 * 128 + q * 8;
#pragma unroll
        for (int c4 = 0; c4 < 4; ++c4) {
          bfr[cur ^ 1][c4][0] = *(const short8*)(wk + c4 * 32);
          bfr[cur ^ 1][c4][1] = *(const short8*)(wk + 2048 + c4 * 32);
        }
      }
#pragma unroll
      for (int mf = 0; mf < 3; ++mf) {
        int pix = wm0 + mf * 16 + r16 + kx;
        const char* ab = (const char*)tbuf + pix * 256;
        int sw = (pix & 15) << 4;
        short8 a0 = *(const short8*)(ab + ((q << 4) ^ sw));
        short8 a1 = *(const short8*)(ab + (((4 + q) << 4) ^ sw));
        short8 a2 = *(const short8*)(ab + (((8 + q) << 4) ^ sw));
        short8 a3 = *(const short8*)(ab + (((12 + q) << 4) ^ sw));
        acc[mf][0] = MFMA(a0, bfr[cur][0][0], acc[mf][0]); acc[mf][1] = MFMA(a0, bfr[cur][0][1], acc[mf][1]);
        acc[mf][0] = MFMA(a1, bfr[cur][1][0], acc[mf][0]); acc[mf][1] = MFMA(a1, bfr[cur][1][1], acc[mf][1]);
        acc[mf][0] = MFMA(a2, bfr[cur][2][0], acc[mf][0]); acc[mf][1] = MFMA(a2, bfr[cur][2][1], acc[mf][1]);
        acc[mf][0] = MFMA(a3, bfr[cur][3][0], acc[mf][0]); acc[mf][1] = MFMA(a3, bfr[cur][3][1], acc[mf][1]);
      }
    }
  }
#pragma unroll
  for (int mf = 0; mf < 3; ++mf)
#pragma unroll
    for (int nf = 0; nf < 2; ++nf) {
      int co = nf * 16 + r16;
      if (co < 27) {
        f32x4 v = acc[mf][nf];
        if (co >= 18) {
          v[0] = 2.f / (1.f + expf(-v[0])); v[1] = 2.f / (1.f + expf(-v[1]));
          v[2] = 2.f / (1.f + expf(-v[2])); v[3] = 2.f / (1.f + expf(-v[3]));
        }
        *(f32x4*)&om[((size_t)(b * 27 + co)) * HWSZ + h * WSZ + wm0 + mf * 16 + q * 4] = v;
      }
    }
}

// ------------- standalone conv kernel (conv2, final) -------------
template<int OUT_MODE, bool RELU, bool MEANACC>
__global__ __launch_bounds__(256, 3) void conv_mfma_k(
    const __hip_bfloat16* __restrict__ inp, const short* __restrict__ wt,
    const float* __restrict__ bias, __hip_bfloat16* __restrict__ outB,
    float* __restrict__ outF, float* __restrict__ meanout) {
  __shared__ __align__(16) short tile[2 * 12800];
  __shared__ float smean[256];
  conv_body<OUT_MODE, RELU, MEANACC>(blockIdx.x, tile, smean, inp, wt, bias, outB, outF, meanout);
}

// ------------- merged conv1 || offmask launch (per-XCD interleave via 8-block groups) -------------
__global__ __launch_bounds__(256, 3) void c1om_k(
    const __hip_bfloat16* __restrict__ xn, const short* __restrict__ wt1,
    const float* __restrict__ rb1, __hip_bfloat16* __restrict__ r1,
    const __hip_bfloat16* __restrict__ cat, const short* __restrict__ wtom,
    const float* __restrict__ obb, float* __restrict__ omb) {
  __shared__ __align__(16) short tile[2 * 12800];   // 51200 B, shared by both paths
  int g = blockIdx.x >> 3;
  int vid = ((g >> 1) << 3) | (blockIdx.x & 7);
  if ((g & 1) == 0)
    conv_body<0, true, false>(vid, tile, nullptr, xn, wt1, rb1, r1, nullptr, nullptr);
  else
    offmask_body(vid, tile, cat, wtom, obb, omb);
}

// ------------- out1 = res*sigmoid(CA(mean)) + x, IN-PLACE on res -------------
__global__ __launch_bounds__(256) void out1_k(__hip_bfloat16* __restrict__ res, const __hip_bfloat16* __restrict__ xn,
    const float* __restrict__ mean, const float* __restrict__ w1, const float* __restrict__ b1,
    const float* __restrict__ w2, const float* __restrict__ b2) {
  int idx = blockIdx.x * 256 + threadIdx.x;
  int b = idx / 294912; int rem = idx - b * 294912;
  int p = rem >> 3, c8 = rem & 7;
  int lane = threadIdx.x & 63, wid = threadIdx.x >> 6;

  __shared__ float s_t[4];
  {
    float prod = w1[wid * 64 + lane] * mean[b * 64 + lane];
#pragma unroll
    for (int m = 1; m < 64; m <<= 1) prod += __shfl_xor(prod, m);
    if (lane == 0) s_t[wid] = fmaxf(prod + b1[wid], 0.f);
  }
  __syncthreads();
  float t0 = s_t[0], t1 = s_t[1], t2 = s_t[2], t3 = s_t[3];

  int hh = p / WSZ, ww = p - hh * WSZ;
  size_t off = ((size_t)b * PP + (size_t)(hh + 1) * PH + ww + 1) * 64 + c8 * 8;
  __hip_bfloat16* rp = res + off;
  const __hip_bfloat16* xp = xn + off;
  unsigned pk[4];
#pragma unroll
  for (int t = 0; t < 4; ++t) {
    float y0, y1;
    {
      int c = c8 * 8 + 2 * t;
      const float4 wv0 = *(const float4*)&w2[c * 4];
      const float4 wv1 = *(const float4*)&w2[(c + 1) * 4];
      float v0 = b2[c]     + wv0.x * t0 + wv0.y * t1 + wv0.z * t2 + wv0.w * t3;
      float v1 = b2[c + 1] + wv1.x * t0 + wv1.y * t1 + wv1.z * t2 + wv1.w * t3;
      y0 = 1.f / (1.f + expf(-v0));
      y1 = 1.f / (1.f + expf(-v1));
    }
    float o0 = bf2f(rp[2 * t]) * y0 + bf2f(xp[2 * t]);
    float o1 = bf2f(rp[2 * t + 1]) * y1 + bf2f(xp[2 * t + 1]);
    pk[t] = (unsigned)f2bf(o0) | ((unsigned)f2bf(o1) << 16);
  }
  *(uint4*)rp = make_uint4(pk[0], pk[1], pk[2], pk[3]);
}

// ------------- deformable conv: 128 px/block (512 thr); FIXED per-pixel epilogue addressing -------------
__global__ __launch_bounds__(512) void deform_mfma_k(
    const __hip_bfloat16* __restrict__ nhwc, const float* __restrict__ om,
    const short* __restrict__ wtb, __hip_bfloat16* __restrict__ fin) {
  // XCD-chunked swizzle: 1152 blocks, 8 XCDs, 144 contiguous per XCD
  int blk = (blockIdx.x & 7) * 144 + (blockIdx.x >> 3);
  int b = blk / 288;
  int p0 = (blk - b * 288) * 128;
  int tid = threadIdx.x, lane = tid & 63, wid = tid >> 6;
  int q = lane >> 4, r16 = lane & 15;
  __shared__ __align__(16) short sA[2][128][64];   // 2 x 16384 B slice buffers, rows 128 B XOR-swizzled
  __shared__ __half2 s_bw[2][9][128];
  __shared__ int s_pk[9][128];

  const float* omb = om + (size_t)b * 27 * HWSZ + p0;
  // phase 1: bilinear corner weights + packed indices (1152 tasks)
  for (int e = tid; e < 1152; e += 512) {
    int kk = e >> 7, pix = e & 127;
    int p = p0 + pix;
    int h = p / WSZ, w2 = p - h * WSZ;
    float oy = omb[(size_t)(2 * kk) * HWSZ + pix];
    float ox = omb[(size_t)(2 * kk + 1) * HWSZ + pix];
    float m2 = omb[(size_t)(18 + kk) * HWSZ + pix];
    float ys = (float)(h + kk / 3 - 1) + oy;
    float xs = (float)(w2 + kk % 3 - 1) + ox;
    float y0f = floorf(ys), x0f = floorf(xs);
    float wy1 = ys - y0f, wx1 = xs - x0f;
    float wy0 = 1.f - wy1, wx0 = 1.f - wx1;
    int y0 = (int)y0f, x0i = (int)x0f;
    int y1 = y0 + 1, x1 = x0i + 1;
    float vy0 = (y0 >= 0 && y0 < HSZ) ? 1.f : 0.f;
    float vx0 = (x0i >= 0 && x0i < WSZ) ? 1.f : 0.f;
    float vy1 = (y1 >= 0 && y1 < HSZ) ? 1.f : 0.f;
    float vx1 = (x1 >= 0 && x1 < WSZ) ? 1.f : 0.f;
    int y0c = min(max(y0, 0), HSZ - 1), x0c = min(max(x0i, 0), WSZ - 1);
    int y1c = min(max(y1, 0), HSZ - 1), x1c = min(max(x1, 0), WSZ - 1);
    s_bw[0][kk][pix] = __floats2half2_rn(wy0 * wx0 * m2 * vy0 * vx0, wy0 * wx1 * m2 * vy0 * vx1);
    s_bw[1][kk][pix] = __floats2half2_rn(wy1 * wx0 * m2 * vy1 * vx0, wy1 * wx1 * m2 * vy1 * vx1);
    s_pk[kk][pix] = ((((y0c + 1) * PH) + x0c + 1) << 2) | ((y1c - y0c) << 1) | (x1c - x0c);
  }
  __syncthreads();

  const __hip_bfloat16* nb = nhwc + (size_t)b * PP * 64;
  // CONTIGUOUS mapping: 4 lanes per pixel, each lane 32 B (2 uint4) per corner
  const int spix = tid >> 2, lg = tid & 3;
  const int rsw = (r16 & 7) << 4;

  uint4 Pa0, Pb0, Qa0, Qb0, Ra0, Rb0, Sa0, Sb0;
  uint4 Pa1, Pb1, Qa1, Qb1, Ra1, Rb1, Sa1, Sb1;
  float2 wab0, wcd0, wab1, wcd1;

#define ISSUE_R(KK, Pa,Pb,Qa,Qb,Ra,Rb,Sa,Sb, Wab, Wcd) do { \
    Wab = __half22float2(s_bw[0][KK][spix]); \
    Wcd = __half22float2(s_bw[1][KK][spix]); \
    int pk_ = s_pk[KK][spix]; \
    int i00_ = pk_ >> 2, dy_ = (pk_ >> 1) & 1, dx_ = pk_ & 1; \
    const __hip_bfloat16* g_ = nb + (size_t)i00_ * 64 + lg * 16; \
    Pa = *(const uint4*)g_;                     Pb = *(const uint4*)(g_ + 8); \
    Qa = *(const uint4*)(g_ + dx_ * 64);        Qb = *(const uint4*)(g_ + dx_ * 64 + 8); \
    Ra = *(const uint4*)(g_ + dy_ * (PH * 64)); Rb = *(const uint4*)(g_ + dy_ * (PH * 64) + 8); \
    Sa = *(const uint4*)(g_ + (dy_ * PH + dx_) * 64); Sb = *(const uint4*)(g_ + (dy_ * PH + dx_) * 64 + 8); \
  } while (0)
#define CMB(J, PA,QA,RA,SA, Wab, Wcd, OUT) do { \
    const unsigned* pa_ = (const unsigned*)&PA; const unsigned* qa_ = (const unsigned*)&QA; \
    const unsigned* ra_ = (const unsigned*)&RA; const unsigned* sa_ = (const unsigned*)&SA; \
    float lo_ = Wab.x * bflo(pa_[J]) + Wab.y * bflo(qa_[J]) + Wcd.x * bflo(ra_[J]) + Wcd.y * bflo(sa_[J]); \
    float hi_ = Wab.x * bfhi(pa_[J]) + Wab.y * bfhi(qa_[J]) + Wcd.x * bfhi(ra_[J]) + Wcd.y * bfhi(sa_[J]); \
    OUT = (unsigned)f2bf(lo_) | ((unsigned)f2bf(hi_) << 16); \
  } while (0)
#define CSTORE_R(BUFOFF, Pa,Pb,Qa,Qb,Ra,Rb,Sa,Sb, Wab, Wcd) do { \
    unsigned oa_[4], ob_[4]; \
    CMB(0, Pa,Qa,Ra,Sa, Wab, Wcd, oa_[0]); CMB(1, Pa,Qa,Ra,Sa, Wab, Wcd, oa_[1]); \
    CMB(2, Pa,Qa,Ra,Sa, Wab, Wcd, oa_[2]); CMB(3, Pa,Qa,Ra,Sa, Wab, Wcd, oa_[3]); \
    CMB(0, Pb,Qb,Rb,Sb, Wab, Wcd, ob_[0]); CMB(1, Pb,Qb,Rb,Sb, Wab, Wcd, ob_[1]); \
    CMB(2, Pb,Qb,Rb,Sb, Wab, Wcd, ob_[2]); CMB(3, Pb,Qb,Rb,Sb, Wab, Wcd, ob_[3]); \
    char* dst_ = (char*)sA + (BUFOFF) + spix * 128; \
    *(uint4*)(dst_ + ((((lg * 2) ^ (spix & 7))) << 4))     = make_uint4(oa_[0], oa_[1], oa_[2], oa_[3]); \
    *(uint4*)(dst_ + ((((lg * 2 + 1) ^ (spix & 7))) << 4)) = make_uint4(ob_[0], ob_[1], ob_[2], ob_[3]); \
  } while (0)

  ISSUE_R(0, Pa0,Pb0,Qa0,Qb0,Ra0,Rb0,Sa0,Sb0, wab0, wcd0);
  CSTORE_R(0, Pa0,Pb0,Qa0,Qb0,Ra0,Rb0,Sa0,Sb0, wab0, wcd0);
  ISSUE_R(1, Pa0,Pb0,Qa0,Qb0,Ra0,Rb0,Sa0,Sb0, wab0, wcd0);
  ISSUE_R(2, Pa1,Pb1,Qa1,Qb1,Ra1,Rb1,Sa1,Sb1, wab1, wcd1);

  f32x4 acc0 = (f32x4){0.f, 0.f, 0.f, 0.f};
  f32x4 acc1 = (f32x4){0.f, 0.f, 0.f, 0.f};
  f32x4 acc2 = (f32x4){0.f, 0.f, 0.f, 0.f};
  f32x4 acc3 = (f32x4){0.f, 0.f, 0.f, 0.f};
  const int cs = wid & 3, ph = wid >> 2;           // co-slice, pixel-half
  const short* wrow = wtb + (size_t)(cs * 16 + r16) * 576;
  const char* a0base = (const char*)sA + (ph * 64 + r16) * 128;
  const char* a1base = (const char*)sA + (ph * 64 + r16 + 16) * 128;
  const char* a2base = (const char*)sA + (ph * 64 + r16 + 32) * 128;
  const char* a3base = (const char*)sA + (ph * 64 + r16 + 48) * 128;

#pragma unroll
  for (int kk = 0; kk < 9; ++kk) {
    const int bo = (kk & 1) * 16384;
    __syncthreads();
#pragma unroll
    for (int s = 0; s < 2; ++s) {
      short8 wf = *(const short8*)(wrow + kk * 64 + s * 32 + q * 8);
      int off = bo + ((s * 64 + q * 16) ^ rsw);
      acc0 = MFMA(wf, *(const short8*)(a0base + off), acc0);
      acc1 = MFMA(wf, *(const short8*)(a1base + off), acc1);
      acc2 = MFMA(wf, *(const short8*)(a2base + off), acc2);
      acc3 = MFMA(wf, *(const short8*)(a3base + off), acc3);
    }
    if (kk < 8) {
      const int nbo = ((kk + 1) & 1) * 16384;
      if ((kk & 1) == 0) {
        CSTORE_R(nbo, Pa0,Pb0,Qa0,Qb0,Ra0,Rb0,Sa0,Sb0, wab0, wcd0);
        if (kk + 3 <= 8) ISSUE_R(kk + 3, Pa0,Pb0,Qa0,Qb0,Ra0,Rb0,Sa0,Sb0, wab0, wcd0);
      } else {
        CSTORE_R(nbo, Pa1,Pb1,Qa1,Qb1,Ra1,Rb1,Sa1,Sb1, wab1, wcd1);
        if (kk + 3 <= 8) ISSUE_R(kk + 3, Pa1,Pb1,Qa1,Qb1,Ra1,Rb1,Sa1,Sb1, wab1, wcd1);
      }
    }
  }

  // epilogue: +out1 residual, pack bf16, NHWC store.
  // FIX: 128-px blocks cross padded-row boundaries (192 % 128 != 0) -> per-pixel addressing.
  __hip_bfloat16* fb = fin + (size_t)b * PP * 64;
#pragma unroll
  for (int nf = 0; nf < 4; ++nf) {
    f32x4 av = nf == 0 ? acc0 : nf == 1 ? acc1 : nf == 2 ? acc2 : acc3;
    int pix = ph * 64 + nf * 16 + r16;
    int p = p0 + pix;
    int hh = p / WSZ, ww = p - hh * WSZ;
    size_t po = ((size_t)(hh + 1) * PH + ww + 1) * 64;
    int co = cs * 16 + q * 4;
    const unsigned* rr = (const unsigned*)(nb + po + co);
    unsigned r0 = rr[0], r1 = rr[1];
    float o0 = av[0] + bflo(r0);
    float o1 = av[1] + bfhi(r0);
    float o2 = av[2] + bflo(r1);
    float o3 = av[3] + bfhi(r1);
    uint2 pk2 = make_uint2((unsigned)f2bf(o0) | ((unsigned)f2bf(o1) << 16),
                           (unsigned)f2bf(o2) | ((unsigned)f2bf(o3) << 16));
    *(uint2*)(fb + po + co) = pk2;
  }
#undef ISSUE_R
#undef CMB
#undef CSTORE_R
}

extern "C" void kernel_launch(void* const* d_in, const int* in_sizes, int n_in,
                              void* d_out, int out_size, void* d_ws, size_t ws_size,
                              hipStream_t stream) {
  (void)in_sizes; (void)n_in; (void)out_size; (void)ws_size;
  const float* x     = (const float*)d_in[0];
  const float* inter = (const float*)d_in[1];
  const float* fea   = (const float*)d_in[2];
  const float* rw1   = (const float*)d_in[3];
  const float* rb1   = (const float*)d_in[4];
  const float* rw2   = (const float*)d_in[5];
  const float* rb2   = (const float*)d_in[6];
  const float* caw1  = (const float*)d_in[7];
  const float* cab1  = (const float*)d_in[8];
  const float* caw2  = (const float*)d_in[9];
  const float* cab2  = (const float*)d_in[10];
  const float* offw  = (const float*)d_in[11];
  const float* offb  = (const float*)d_in[12];
  const float* maskw = (const float*)d_in[13];
  const float* maskb = (const float*)d_in[14];
  const float* dw    = (const float*)d_in[15];
  const float* cw    = (const float*)d_in[16];
  const float* cb    = (const float*)d_in[17];

  char* w = (char*)d_ws;
  const size_t P64 = (size_t)NB * PP * 64 * 2 + 4096;
  const size_t PCAT = (size_t)NB * PP * 128 * 2 + 4096;
  __hip_bfloat16* xn   = (__hip_bfloat16*)(w);
  __hip_bfloat16* r1   = (__hip_bfloat16*)(w + P64);
  __hip_bfloat16* res  = (__hip_bfloat16*)(w + 2 * P64);   // conv2 out; out1 in-place; deform residual/src
  float* omb           = (float*)(w + 3 * P64);            // dedicated offset/mask buffer (15.9 MB < P64)
  __hip_bfloat16* cat  = (__hip_bfloat16*)(w + 4 * P64);
  char* tail = w + 4 * P64 + PCAT;
  short* wt1  = (short*)tail; tail += 73728;
  short* wt2c = (short*)tail; tail += 73728;
  short* wtf  = (short*)tail; tail += 73728;
  short* wtom = (short*)tail; tail += 73728;
  float* obb  = (float*)tail; tail += 128;
  short* wtb  = (short*)tail; tail += 73728;
  float* mean = (float*)tail; tail += 1024;
  __hip_bfloat16* fin = r1;         // overlay: fin reuses r1 slot (r1 dead after conv2)

  zb2_k<<<dim3(194, 4), 256, 0, stream>>>(xn, r1, res, cat);
  wts_k<<<dim3(144, 5), 256, 0, stream>>>(rw1, rw2, cw, offw, maskw, offb, maskb, dw,
                                          wt1, wt2c, wtf, wtom, obb, wtb, mean);
  cvt_k<<<dim3(576, 4, 3), 256, 0, stream>>>(x, inter, fea, xn, cat);

  c1om_k<<<1536, 256, 0, stream>>>(xn, wt1, rb1, r1, cat, wtom, obb, omb);
  conv_mfma_k<0, false, true ><<<768, 256, 0, stream>>>(r1, wt2c, rb2, res, nullptr, mean);
  out1_k<<<4608, 256, 0, stream>>>(res, xn, mean, caw1, cab1, caw2, cab2);
  deform_mfma_k<<<NB * 288, 512, 0, stream>>>(res, omb, wtb, fin);
  conv_mfma_k<1, false, false><<<768, 256, 0, stream>>>(fin, wtf, cb, nullptr, (float*)d_out, nullptr);
}

// Round 17
// 257.493 us; speedup vs baseline: 1.3283x; 1.3283x over previous
//
#include <hip/hip_runtime.h>
#include <hip/hip_bf16.h>
#include <hip/hip_fp16.h>
#include <math.h>

#define HSZ 192
#define WSZ 192
#define HWSZ (192*192)
#define PH 194                 // padded dim
#define PP (PH*PH)             // 37636 padded pixels
#define NB 4

typedef __attribute__((ext_vector_type(8))) short short8;
typedef __attribute__((ext_vector_type(4))) float f32x4;

__device__ inline unsigned short f2bf(float f) { __hip_bfloat16 h = __float2bfloat16(f); return *(unsigned short*)&h; }
__device__ inline float bf2f(__hip_bfloat16 h) { return __bfloat162float(h); }
__device__ inline float bflo(unsigned u) { return __uint_as_float(u << 16); }
__device__ inline float bfhi(unsigned u) { return __uint_as_float(u & 0xffff0000u); }

#define GLDS(SRC, DST) __builtin_amdgcn_global_load_lds( \
    (const __attribute__((address_space(1))) unsigned int*)(const void*)(SRC), \
    (__attribute__((address_space(3))) unsigned int*)(void*)(DST), 16, 0, 0)

#define MFMA(A,B,C) __builtin_amdgcn_mfma_f32_16x16x32_bf16((A),(B),(C),0,0,0)

// ------------- merged border-zero (4 buffers) -------------
__global__ void zb2_k(__hip_bfloat16* xn, __hip_bfloat16* r1, __hip_bfloat16* res,
                      __hip_bfloat16* cat) {
  int job = blockIdx.y;
  __hip_bfloat16* buf = job == 0 ? xn : job == 1 ? r1 : job == 2 ? res : cat;
  int Cn = (job == 3) ? 128 : 64;
  int cg8 = Cn >> 3;
  int tot = NB * 772 * cg8;
  int idx = blockIdx.x * 256 + threadIdx.x;
  if (idx >= tot) return;
  int cg = idx % cg8; int rem = idx / cg8;
  int e = rem % 772; int b = rem / 772;
  int h, w2;
  if (e < 194) { h = 0; w2 = e; }
  else if (e < 388) { h = 193; w2 = e - 194; }
  else if (e < 580) { h = e - 388 + 1; w2 = 0; }
  else { h = e - 580 + 1; w2 = 193; }
  uint4 z = make_uint4(0, 0, 0, 0);
  *(uint4*)&buf[(((size_t)b * PH + h) * PH + w2) * Cn + cg * 8] = z;
}

// ------------- merged weight prep (5 jobs) + mean zero -------------
__global__ void wts_k(const float* __restrict__ rw1, const float* __restrict__ rw2,
                      const float* __restrict__ cw, const float* __restrict__ offw,
                      const float* __restrict__ maskw, const float* __restrict__ offb,
                      const float* __restrict__ maskb, const float* __restrict__ dwv,
                      short* wt1, short* wt2c, short* wtf, short* wtom, float* ob,
                      short* wtb, float* meanz) {
  int job = blockIdx.y;
  int idx = blockIdx.x * 256 + threadIdx.x;   // < 36864
  if (job < 3) {
    const float* src = job == 0 ? rw1 : job == 1 ? rw2 : cw;
    short* dst = job == 0 ? wt1 : job == 1 ? wt2c : wtf;
    int kk = idx >> 12, rem = idx & 4095;
    int co = rem >> 6, ci = rem & 63;
    dst[idx] = (short)f2bf(src[(co * 64 + ci) * 9 + kk]);
  } else if (job == 3) {
    int kk = idx >> 12, rem = idx & 4095;
    int co = rem >> 7, ci = rem & 127;
    float v = 0.f;
    if (co < 18) v = offw[(co * 128 + ci) * 9 + kk];
    else if (co < 27) v = maskw[((co - 18) * 128 + ci) * 9 + kk];
    wtom[idx] = (short)f2bf(v);
    if (idx < 32) ob[idx] = idx < 18 ? offb[idx] : (idx < 27 ? maskb[idx - 18] : 0.f);
  } else {
    int o = idx / 576, rem = idx - o * 576;
    int kk = rem >> 6, ci = rem & 63;
    wtb[idx] = (short)f2bf(dwv[(o * 64 + ci) * 9 + kk]);
    if (blockIdx.x == 0 && threadIdx.x < 256) meanz[threadIdx.x] = 0.f;
  }
}

// ------------- merged NCHW f32 -> padded NHWC bf16 (x -> xn, inter/fea -> cat) -------------
__global__ __launch_bounds__(256) void cvt_k(const float* __restrict__ x,
    const float* __restrict__ inter, const float* __restrict__ fea,
    __hip_bfloat16* __restrict__ xn, __hip_bfloat16* __restrict__ cat) {
  int job = blockIdx.z;
  const float* src = job == 0 ? x : job == 1 ? inter : fea;
  __hip_bfloat16* dst = job == 0 ? xn : cat;
  int Cdst = job == 0 ? 64 : 128;
  int coff = job == 2 ? 64 : 0;
  __shared__ float s[64][65];
  int p0 = blockIdx.x * 64; int b = blockIdx.y;
  int lane = threadIdx.x & 63, g = threadIdx.x >> 6;
#pragma unroll
  for (int i = 0; i < 16; ++i) {
    int c = i * 4 + g;
    s[c][lane] = src[((size_t)b * 64 + c) * HWSZ + p0 + lane];
  }
  __syncthreads();
  int pix = threadIdx.x >> 2, cg = threadIdx.x & 3;
  int h = p0 / WSZ, w0 = p0 - h * WSZ + pix;
  size_t addr = (((size_t)b * PH + h + 1) * PH + 1 + w0) * Cdst + coff + cg * 16;
  unsigned pk2[8];
#pragma unroll
  for (int t = 0; t < 8; ++t)
    pk2[t] = (unsigned)f2bf(s[cg * 16 + 2 * t][pix]) | ((unsigned)f2bf(s[cg * 16 + 2 * t + 1][pix]) << 16);
  *(uint4*)&dst[addr]     = make_uint4(pk2[0], pk2[1], pk2[2], pk2[3]);
  *(uint4*)&dst[addr + 8] = make_uint4(pk2[4], pk2[5], pk2[6], pk2[7]);
}

// ------------- conv3x3 body (row-dbuf, validated R13/R14); tbuf = 2 x 12800 shorts -------------
template<int OUT_MODE, bool RELU, bool MEANACC>
__device__ __forceinline__ void conv_body(int vbid, short* tbuf, float* smean,
    const __hip_bfloat16* __restrict__ inp, const short* __restrict__ wt,
    const float* __restrict__ bias, __hip_bfloat16* __restrict__ outB,
    float* __restrict__ outF, float* __restrict__ meanout) {
  int flat = (vbid & 7) * 96 + (vbid >> 3);
  const int b = flat / 192, h = flat - (flat / 192) * 192;
  const int tid = threadIdx.x, lane = tid & 63, wid = tid >> 6;
  const int q = lane >> 4, r16 = lane & 15;

  const __hip_bfloat16* base = inp + ((size_t)b * PH + h) * (PH * 64);
#define STAGE(BUF, R) do { \
    const char* gb_ = (const char*)(base + (size_t)(R) * (PH * 64)); \
    for (int s_ = wid; s_ < 25; s_ += 4) { \
      int pix_ = 8 * s_ + (lane >> 3); \
      const char* src_ = gb_ + pix_ * 128 + ((((lane & 7) ^ ((lane >> 3) & 7))) << 4); \
      GLDS(src_, tbuf + (BUF) * 12800 + s_ * 512); \
    } \
  } while (0)

  STAGE(0, 0);

  f32x4 acc[3][4];
  if (OUT_MODE == 0) {
#pragma unroll
    for (int nf = 0; nf < 4; ++nf) {
      float4 bv = *(const float4*)&bias[nf * 16 + q * 4];
      f32x4 v; v[0] = bv.x; v[1] = bv.y; v[2] = bv.z; v[3] = bv.w;
      acc[0][nf] = v; acc[1][nf] = v; acc[2][nf] = v;
    }
  } else {
#pragma unroll
    for (int nf = 0; nf < 4; ++nf) {
      float bs = bias[nf * 16 + r16];
      f32x4 v; v[0] = bs; v[1] = bs; v[2] = bs; v[3] = bs;
      acc[0][nf] = v; acc[1][nf] = v; acc[2][nf] = v;
    }
  }

  short8 bfr[2][2][4];
  {
    const short* wk0 = wt + r16 * 64 + q * 8;
#pragma unroll
    for (int nf = 0; nf < 4; ++nf) {
      bfr[0][0][nf] = *(const short8*)(wk0 + nf * 1024);
      bfr[0][1][nf] = *(const short8*)(wk0 + nf * 1024 + 32);
    }
  }
  __syncthreads();

  const int wm0 = wid * 48;
#pragma unroll
  for (int ky = 0; ky < 3; ++ky) {
    const int cb = ky & 1;
    if (ky < 2) STAGE(cb ^ 1, ky + 1);
#pragma unroll
    for (int kx = 0; kx < 3; ++kx) {
      const int kk = ky * 3 + kx;
      const int cur = kk & 1;
      if (kk < 8) {
        const short* wk = wt + (kk + 1) * 4096 + r16 * 64 + q * 8;
#pragma unroll
        for (int nf = 0; nf < 4; ++nf) {
          bfr[cur ^ 1][0][nf] = *(const short8*)(wk + nf * 1024);
          bfr[cur ^ 1][1][nf] = *(const short8*)(wk + nf * 1024 + 32);
        }
      }
#pragma unroll
      for (int mf = 0; mf < 3; ++mf) {
        int pix = wm0 + mf * 16 + r16 + kx;
        const char* ab = (const char*)(tbuf + cb * 12800) + pix * 128;
        int sw = (pix & 7) << 4;
        short8 a0 = *(const short8*)(ab + ((q << 4) ^ sw));
        short8 a1 = *(const short8*)(ab + (((q + 4) << 4) ^ sw));
#pragma unroll
        for (int nf = 0; nf < 4; ++nf) {
          if (OUT_MODE == 0) {
            acc[mf][nf] = MFMA(bfr[cur][0][nf], a0, acc[mf][nf]);
            acc[mf][nf] = MFMA(bfr[cur][1][nf], a1, acc[mf][nf]);
          } else {
            acc[mf][nf] = MFMA(a0, bfr[cur][0][nf], acc[mf][nf]);
            acc[mf][nf] = MFMA(a1, bfr[cur][1][nf], acc[mf][nf]);
          }
        }
      }
    }
    __syncthreads();
  }
#undef STAGE

  if (MEANACC) {
    float t[4][4];
#pragma unroll
    for (int nf = 0; nf < 4; ++nf)
#pragma unroll
      for (int rg = 0; rg < 4; ++rg)
        t[nf][rg] = acc[0][nf][rg] + acc[1][nf][rg] + acc[2][nf][rg];
#pragma unroll
    for (int m = 1; m < 16; m <<= 1)
#pragma unroll
      for (int nf = 0; nf < 4; ++nf)
#pragma unroll
        for (int rg = 0; rg < 4; ++rg)
          t[nf][rg] += __shfl_xor(t[nf][rg], m);
    if (r16 == 0)
#pragma unroll
      for (int nf = 0; nf < 4; ++nf)
#pragma unroll
        for (int rg = 0; rg < 4; ++rg)
          smean[wid * 64 + nf * 16 + q * 4 + rg] = t[nf][rg];
    __syncthreads();
    if (tid < 64)
      atomicAdd(&meanout[b * 64 + tid],
                (smean[tid] + smean[64 + tid] + smean[128 + tid] + smean[192 + tid]) * (1.f / 36864.f));
  }

  if (OUT_MODE == 0) {
    short* t1 = tbuf + 12800;
#pragma unroll
    for (int mf = 0; mf < 3; ++mf)
#pragma unroll
      for (int nf = 0; nf < 4; ++nf) {
        f32x4 v = acc[mf][nf];
        if (RELU) { v[0] = fmaxf(v[0], 0.f); v[1] = fmaxf(v[1], 0.f); v[2] = fmaxf(v[2], 0.f); v[3] = fmaxf(v[3], 0.f); }
        unsigned lo = (unsigned)f2bf(v[0]) | ((unsigned)f2bf(v[1]) << 16);
        unsigned hi = (unsigned)f2bf(v[2]) | ((unsigned)f2bf(v[3]) << 16);
        int pix = wm0 + mf * 16 + r16;
        int byteoff = (pix * 128 + nf * 32 + q * 8) ^ ((pix & 7) << 4);
        *(uint2*)((char*)t1 + byteoff) = make_uint2(lo, hi);
      }
    __syncthreads();
    char* orow = (char*)outB + ((((size_t)b * PH + h + 1) * PH + 1) * 64) * 2;
    for (int s = wid; s < 24; s += 4) {
      int pix = 8 * s + (lane >> 3);
      int g16 = ((lane & 7) ^ (pix & 7)) << 4;
      uint4 d = *(const uint4*)((const char*)t1 + pix * 128 + g16);
      *(uint4*)(orow + pix * 128 + ((lane & 7) << 4)) = d;
    }
  } else {
    float* ob2 = outF + (size_t)b * 64 * HWSZ + h * WSZ;
#pragma unroll
    for (int mf = 0; mf < 3; ++mf)
#pragma unroll
      for (int nf = 0; nf < 4; ++nf) {
        int pix0 = wm0 + mf * 16 + q * 4;
        int co = nf * 16 + r16;
        *(f32x4*)&ob2[(size_t)co * HWSZ + pix0] = acc[mf][nf];
      }
  }
}

// ------------- standalone conv kernel -------------
template<int OUT_MODE, bool RELU, bool MEANACC>
__global__ __launch_bounds__(256, 3) void conv_mfma_k(
    const __hip_bfloat16* __restrict__ inp, const short* __restrict__ wt,
    const float* __restrict__ bias, __hip_bfloat16* __restrict__ outB,
    float* __restrict__ outF, float* __restrict__ meanout) {
  __shared__ __align__(16) short tile[2 * 12800];
  __shared__ float smean[256];
  conv_body<OUT_MODE, RELU, MEANACC>(blockIdx.x, tile, smean, inp, wt, bias, outB, outF, meanout);
}

// ------------- standalone offmask kernel (XCD-chunked vid) -------------
__global__ __launch_bounds__(256, 3) void offmask_mfma_k(
    const __hip_bfloat16* __restrict__ cat, const short* __restrict__ wt2,
    const float* __restrict__ ob, float* __restrict__ om) {
  int flat = (blockIdx.x & 7) * 96 + (blockIdx.x >> 3);
  const int b = flat / 192, h = flat - (flat / 192) * 192;
  const int tid = threadIdx.x, lane = tid & 63, wid = tid >> 6;
  const int q = lane >> 4, r16 = lane & 15;
  __shared__ __align__(16) short tile[200 * 128];      // 51200 B

  f32x4 acc[3][2];
#pragma unroll
  for (int nf = 0; nf < 2; ++nf) {
    float bs = ob[nf * 16 + r16];
    f32x4 v; v[0] = bs; v[1] = bs; v[2] = bs; v[3] = bs;
    acc[0][nf] = v; acc[1][nf] = v; acc[2][nf] = v;
  }
  const char* gb = (const char*)(cat + ((size_t)b * PH + h) * (PH * 128));
  const int wm0 = wid * 48;

  short8 bfr[2][4][2];
  {
    const short* wk0 = wt2 + r16 * 128 + q * 8;
#pragma unroll
    for (int c4 = 0; c4 < 4; ++c4) {
      bfr[0][c4][0] = *(const short8*)(wk0 + c4 * 32);
      bfr[0][c4][1] = *(const short8*)(wk0 + 2048 + c4 * 32);
    }
  }

#pragma unroll
  for (int r = 0; r < 3; ++r) {
    __syncthreads();
    for (int s = wid; s < 50; s += 4) {
      int pix = 4 * s + (lane >> 4);
      const char* src = gb + (size_t)r * (PH * 256) + pix * 256
                      + ((((lane & 15) ^ (pix & 15))) << 4);
      GLDS(src, tile + s * 512);
    }
    __syncthreads();
#pragma unroll
    for (int kx = 0; kx < 3; ++kx) {
      const int kk = r * 3 + kx;
      const int cur = kk & 1;
      if (kk < 8) {
        const short* wk = wt2 + (kk + 1) * 4096 + r16 * 128 + q * 8;
#pragma unroll
        for (int c4 = 0; c4 < 4; ++c4) {
          bfr[cur ^ 1][c4][0] = *(const short8*)(wk + c4 * 32);
          bfr[cur ^ 1][c4][1] = *(const short8*)(wk + 2048 + c4 * 32);
        }
      }
#pragma unroll
      for (int mf = 0; mf < 3; ++mf) {
        int pix = wm0 + mf * 16 + r16 + kx;
        const char* ab = (const char*)tile + pix * 256;
        int sw = (pix & 15) << 4;
        short8 a0 = *(const short8*)(ab + ((q << 4) ^ sw));
        short8 a1 = *(const short8*)(ab + (((4 + q) << 4) ^ sw));
        short8 a2 = *(const short8*)(ab + (((8 + q) << 4) ^ sw));
        short8 a3 = *(const short8*)(ab + (((12 + q) << 4) ^ sw));
        acc[mf][0] = MFMA(a0, bfr[cur][0][0], acc[mf][0]); acc[mf][1] = MFMA(a0, bfr[cur][0][1], acc[mf][1]);
        acc[mf][0] = MFMA(a1, bfr[cur][1][0], acc[mf][0]); acc[mf][1] = MFMA(a1, bfr[cur][1][1], acc[mf][1]);
        acc[mf][0] = MFMA(a2, bfr[cur][2][0], acc[mf][0]); acc[mf][1] = MFMA(a2, bfr[cur][2][1], acc[mf][1]);
        acc[mf][0] = MFMA(a3, bfr[cur][3][0], acc[mf][0]); acc[mf][1] = MFMA(a3, bfr[cur][3][1], acc[mf][1]);
      }
    }
  }
#pragma unroll
  for (int mf = 0; mf < 3; ++mf)
#pragma unroll
    for (int nf = 0; nf < 2; ++nf) {
      int co = nf * 16 + r16;
      if (co < 27) {
        f32x4 v = acc[mf][nf];
        if (co >= 18) {
          v[0] = 2.f / (1.f + expf(-v[0])); v[1] = 2.f / (1.f + expf(-v[1]));
          v[2] = 2.f / (1.f + expf(-v[2])); v[3] = 2.f / (1.f + expf(-v[3]));
        }
        *(f32x4*)&om[((size_t)(b * 27 + co)) * HWSZ + h * WSZ + wm0 + mf * 16 + q * 4] = v;
      }
    }
}

// ------------- out1 = res*sigmoid(CA(mean)) + x, IN-PLACE on res -------------
__global__ __launch_bounds__(256) void out1_k(__hip_bfloat16* __restrict__ res, const __hip_bfloat16* __restrict__ xn,
    const float* __restrict__ mean, const float* __restrict__ w1, const float* __restrict__ b1,
    const float* __restrict__ w2, const float* __restrict__ b2) {
  int idx = blockIdx.x * 256 + threadIdx.x;
  int b = idx / 294912; int rem = idx - b * 294912;
  int p = rem >> 3, c8 = rem & 7;
  int lane = threadIdx.x & 63, wid = threadIdx.x >> 6;

  __shared__ float s_t[4];
  {
    float prod = w1[wid * 64 + lane] * mean[b * 64 + lane];
#pragma unroll
    for (int m = 1; m < 64; m <<= 1) prod += __shfl_xor(prod, m);
    if (lane == 0) s_t[wid] = fmaxf(prod + b1[wid], 0.f);
  }
  __syncthreads();
  float t0 = s_t[0], t1 = s_t[1], t2 = s_t[2], t3 = s_t[3];

  int hh = p / WSZ, ww = p - hh * WSZ;
  size_t off = ((size_t)b * PP + (size_t)(hh + 1) * PH + ww + 1) * 64 + c8 * 8;
  __hip_bfloat16* rp = res + off;
  const __hip_bfloat16* xp = xn + off;
  unsigned pk[4];
#pragma unroll
  for (int t = 0; t < 4; ++t) {
    float y0, y1;
    {
      int c = c8 * 8 + 2 * t;
      const float4 wv0 = *(const float4*)&w2[c * 4];
      const float4 wv1 = *(const float4*)&w2[(c + 1) * 4];
      float v0 = b2[c]     + wv0.x * t0 + wv0.y * t1 + wv0.z * t2 + wv0.w * t3;
      float v1 = b2[c + 1] + wv1.x * t0 + wv1.y * t1 + wv1.z * t2 + wv1.w * t3;
      y0 = 1.f / (1.f + expf(-v0));
      y1 = 1.f / (1.f + expf(-v1));
    }
    float o0 = bf2f(rp[2 * t]) * y0 + bf2f(xp[2 * t]);
    float o1 = bf2f(rp[2 * t + 1]) * y1 + bf2f(xp[2 * t + 1]);
    pk[t] = (unsigned)f2bf(o0) | ((unsigned)f2bf(o1) << 16);
  }
  *(uint4*)rp = make_uint4(pk[0], pk[1], pk[2], pk[3]);
}

// ------------- deformable conv: 128 px/block (512 thr), per-pixel epilogue addressing -------------
__global__ __launch_bounds__(512) void deform_mfma_k(
    const __hip_bfloat16* __restrict__ nhwc, const float* __restrict__ om,
    const short* __restrict__ wtb, __hip_bfloat16* __restrict__ fin) {
  // XCD-chunked swizzle: 1152 blocks, 8 XCDs, 144 contiguous per XCD
  int blk = (blockIdx.x & 7) * 144 + (blockIdx.x >> 3);
  int b = blk / 288;
  int p0 = (blk - b * 288) * 128;
  int tid = threadIdx.x, lane = tid & 63, wid = tid >> 6;
  int q = lane >> 4, r16 = lane & 15;
  __shared__ __align__(16) short sA[2][128][64];   // 2 x 16384 B slice buffers, rows 128 B XOR-swizzled
  __shared__ __half2 s_bw[2][9][128];
  __shared__ int s_pk[9][128];

  const float* omb = om + (size_t)b * 27 * HWSZ + p0;
  // phase 1: bilinear corner weights + packed indices (1152 tasks)
  for (int e = tid; e < 1152; e += 512) {
    int kk = e >> 7, pix = e & 127;
    int p = p0 + pix;
    int h = p / WSZ, w2 = p - h * WSZ;
    float oy = omb[(size_t)(2 * kk) * HWSZ + pix];
    float ox = omb[(size_t)(2 * kk + 1) * HWSZ + pix];
    float m2 = omb[(size_t)(18 + kk) * HWSZ + pix];
    float ys = (float)(h + kk / 3 - 1) + oy;
    float xs = (float)(w2 + kk % 3 - 1) + ox;
    float y0f = floorf(ys), x0f = floorf(xs);
    float wy1 = ys - y0f, wx1 = xs - x0f;
    float wy0 = 1.f - wy1, wx0 = 1.f - wx1;
    int y0 = (int)y0f, x0i = (int)x0f;
    int y1 = y0 + 1, x1 = x0i + 1;
    float vy0 = (y0 >= 0 && y0 < HSZ) ? 1.f : 0.f;
    float vx0 = (x0i >= 0 && x0i < WSZ) ? 1.f : 0.f;
    float vy1 = (y1 >= 0 && y1 < HSZ) ? 1.f : 0.f;
    float vx1 = (x1 >= 0 && x1 < WSZ) ? 1.f : 0.f;
    int y0c = min(max(y0, 0), HSZ - 1), x0c = min(max(x0i, 0), WSZ - 1);
    int y1c = min(max(y1, 0), HSZ - 1), x1c = min(max(x1, 0), WSZ - 1);
    s_bw[0][kk][pix] = __floats2half2_rn(wy0 * wx0 * m2 * vy0 * vx0, wy0 * wx1 * m2 * vy0 * vx1);
    s_bw[1][kk][pix] = __floats2half2_rn(wy1 * wx0 * m2 * vy1 * vx0, wy1 * wx1 * m2 * vy1 * vx1);
    s_pk[kk][pix] = ((((y0c + 1) * PH) + x0c + 1) << 2) | ((y1c - y0c) << 1) | (x1c - x0c);
  }
  __syncthreads();

  const __hip_bfloat16* nb = nhwc + (size_t)b * PP * 64;
  // CONTIGUOUS mapping: 4 lanes per pixel, each lane 32 B (2 uint4) per corner
  const int spix = tid >> 2, lg = tid & 3;
  const int rsw = (r16 & 7) << 4;

  uint4 Pa0, Pb0, Qa0, Qb0, Ra0, Rb0, Sa0, Sb0;
  uint4 Pa1, Pb1, Qa1, Qb1, Ra1, Rb1, Sa1, Sb1;
  float2 wab0, wcd0, wab1, wcd1;

#define ISSUE_R(KK, Pa,Pb,Qa,Qb,Ra,Rb,Sa,Sb, Wab, Wcd) do { \
    Wab = __half22float2(s_bw[0][KK][spix]); \
    Wcd = __half22float2(s_bw[1][KK][spix]); \
    int pk_ = s_pk[KK][spix]; \
    int i00_ = pk_ >> 2, dy_ = (pk_ >> 1) & 1, dx_ = pk_ & 1; \
    const __hip_bfloat16* g_ = nb + (size_t)i00_ * 64 + lg * 16; \
    Pa = *(const uint4*)g_;                     Pb = *(const uint4*)(g_ + 8); \
    Qa = *(const uint4*)(g_ + dx_ * 64);        Qb = *(const uint4*)(g_ + dx_ * 64 + 8); \
    Ra = *(const uint4*)(g_ + dy_ * (PH * 64)); Rb = *(const uint4*)(g_ + dy_ * (PH * 64) + 8); \
    Sa = *(const uint4*)(g_ + (dy_ * PH + dx_) * 64); Sb = *(const uint4*)(g_ + (dy_ * PH + dx_) * 64 + 8); \
  } while (0)
#define CMB(J, PA,QA,RA,SA, Wab, Wcd, OUT) do { \
    const unsigned* pa_ = (const unsigned*)&PA; const unsigned* qa_ = (const unsigned*)&QA; \
    const unsigned* ra_ = (const unsigned*)&RA; const unsigned* sa_ = (const unsigned*)&SA; \
    float lo_ = Wab.x * bflo(pa_[J]) + Wab.y * bflo(qa_[J]) + Wcd.x * bflo(ra_[J]) + Wcd.y * bflo(sa_[J]); \
    float hi_ = Wab.x * bfhi(pa_[J]) + Wab.y * bfhi(qa_[J]) + Wcd.x * bfhi(ra_[J]) + Wcd.y * bfhi(sa_[J]); \
    OUT = (unsigned)f2bf(lo_) | ((unsigned)f2bf(hi_) << 16); \
  } while (0)
#define CSTORE_R(BUFOFF, Pa,Pb,Qa,Qb,Ra,Rb,Sa,Sb, Wab, Wcd) do { \
    unsigned oa_[4], ob_[4]; \
    CMB(0, Pa,Qa,Ra,Sa, Wab, Wcd, oa_[0]); CMB(1, Pa,Qa,Ra,Sa, Wab, Wcd, oa_[1]); \
    CMB(2, Pa,Qa,Ra,Sa, Wab, Wcd, oa_[2]); CMB(3, Pa,Qa,Ra,Sa, Wab, Wcd, oa_[3]); \
    CMB(0, Pb,Qb,Rb,Sb, Wab, Wcd, ob_[0]); CMB(1, Pb,Qb,Rb,Sb, Wab, Wcd, ob_[1]); \
    CMB(2, Pb,Qb,Rb,Sb, Wab, Wcd, ob_[2]); CMB(3, Pb,Qb,Rb,Sb, Wab, Wcd, ob_[3]); \
    char* dst_ = (char*)sA + (BUFOFF) + spix * 128; \
    *(uint4*)(dst_ + ((((lg * 2) ^ (spix & 7))) << 4))     = make_uint4(oa_[0], oa_[1], oa_[2], oa_[3]); \
    *(uint4*)(dst_ + ((((lg * 2 + 1) ^ (spix & 7))) << 4)) = make_uint4(ob_[0], ob_[1], ob_[2], ob_[3]); \
  } while (0)

  ISSUE_R(0, Pa0,Pb0,Qa0,Qb0,Ra0,Rb0,Sa0,Sb0, wab0, wcd0);
  CSTORE_R(0, Pa0,Pb0,Qa0,Qb0,Ra0,Rb0,Sa0,Sb0, wab0, wcd0);
  ISSUE_R(1, Pa0,Pb0,Qa0,Qb0,Ra0,Rb0,Sa0,Sb0, wab0, wcd0);
  ISSUE_R(2, Pa1,Pb1,Qa1,Qb1,Ra1,Rb1,Sa1,Sb1, wab1, wcd1);

  f32x4 acc0 = (f32x4){0.f, 0.f, 0.f, 0.f};
  f32x4 acc1 = (f32x4){0.f, 0.f, 0.f, 0.f};
  f32x4 acc2 = (f32x4){0.f, 0.f, 0.f, 0.f};
  f32x4 acc3 = (f32x4){0.f, 0.f, 0.f, 0.f};
  const int cs = wid & 3, ph = wid >> 2;           // co-slice, pixel-half
  const short* wrow = wtb + (size_t)(cs * 16 + r16) * 576;
  const char* a0base = (const char*)sA + (ph * 64 + r16) * 128;
  const char* a1base = (const char*)sA + (ph * 64 + r16 + 16) * 128;
  const char* a2base = (const char*)sA + (ph * 64 + r16 + 32) * 128;
  const char* a3base = (const char*)sA + (ph * 64 + r16 + 48) * 128;

#pragma unroll
  for (int kk = 0; kk < 9; ++kk) {
    const int bo = (kk & 1) * 16384;
    __syncthreads();
#pragma unroll
    for (int s = 0; s < 2; ++s) {
      short8 wf = *(const short8*)(wrow + kk * 64 + s * 32 + q * 8);
      int off = bo + ((s * 64 + q * 16) ^ rsw);
      acc0 = MFMA(wf, *(const short8*)(a0base + off), acc0);
      acc1 = MFMA(wf, *(const short8*)(a1base + off), acc1);
      acc2 = MFMA(wf, *(const short8*)(a2base + off), acc2);
      acc3 = MFMA(wf, *(const short8*)(a3base + off), acc3);
    }
    if (kk < 8) {
      const int nbo = ((kk + 1) & 1) * 16384;
      if ((kk & 1) == 0) {
        CSTORE_R(nbo, Pa0,Pb0,Qa0,Qb0,Ra0,Rb0,Sa0,Sb0, wab0, wcd0);
        if (kk + 3 <= 8) ISSUE_R(kk + 3, Pa0,Pb0,Qa0,Qb0,Ra0,Rb0,Sa0,Sb0, wab0, wcd0);
      } else {
        CSTORE_R(nbo, Pa1,Pb1,Qa1,Qb1,Ra1,Rb1,Sa1,Sb1, wab1, wcd1);
        if (kk + 3 <= 8) ISSUE_R(kk + 3, Pa1,Pb1,Qa1,Qb1,Ra1,Rb1,Sa1,Sb1, wab1, wcd1);
      }
    }
  }

  // epilogue: +out1 residual, per-pixel padded addressing (128-px blocks cross rows)
  __hip_bfloat16* fb = fin + (size_t)b * PP * 64;
#pragma unroll
  for (int nf = 0; nf < 4; ++nf) {
    f32x4 av = nf == 0 ? acc0 : nf == 1 ? acc1 : nf == 2 ? acc2 : acc3;
    int pix = ph * 64 + nf * 16 + r16;
    int p = p0 + pix;
    int hh = p / WSZ, ww = p - hh * WSZ;
    size_t po = ((size_t)(hh + 1) * PH + ww + 1) * 64;
    int co = cs * 16 + q * 4;
    const unsigned* rr = (const unsigned*)(nb + po + co);
    unsigned r0 = rr[0], r1 = rr[1];
    float o0 = av[0] + bflo(r0);
    float o1 = av[1] + bfhi(r0);
    float o2 = av[2] + bflo(r1);
    float o3 = av[3] + bfhi(r1);
    uint2 pk2 = make_uint2((unsigned)f2bf(o0) | ((unsigned)f2bf(o1) << 16),
                           (unsigned)f2bf(o2) | ((unsigned)f2bf(o3) << 16));
    *(uint2*)(fb + po + co) = pk2;
  }
#undef ISSUE_R
#undef CMB
#undef CSTORE_R
}

extern "C" void kernel_launch(void* const* d_in, const int* in_sizes, int n_in,
                              void* d_out, int out_size, void* d_ws, size_t ws_size,
                              hipStream_t stream) {
  (void)in_sizes; (void)n_in; (void)out_size; (void)ws_size;
  const float* x     = (const float*)d_in[0];
  const float* inter = (const float*)d_in[1];
  const float* fea   = (const float*)d_in[2];
  const float* rw1   = (const float*)d_in[3];
  const float* rb1   = (const float*)d_in[4];
  const float* rw2   = (const float*)d_in[5];
  const float* rb2   = (const float*)d_in[6];
  const float* caw1  = (const float*)d_in[7];
  const float* cab1  = (const float*)d_in[8];
  const float* caw2  = (const float*)d_in[9];
  const float* cab2  = (const float*)d_in[10];
  const float* offw  = (const float*)d_in[11];
  const float* offb  = (const float*)d_in[12];
  const float* maskw = (const float*)d_in[13];
  const float* maskb = (const float*)d_in[14];
  const float* dw    = (const float*)d_in[15];
  const float* cw    = (const float*)d_in[16];
  const float* cb    = (const float*)d_in[17];

  char* w = (char*)d_ws;
  const size_t P64 = (size_t)NB * PP * 64 * 2 + 4096;
  const size_t PCAT = (size_t)NB * PP * 128 * 2 + 4096;
  __hip_bfloat16* xn   = (__hip_bfloat16*)(w);
  __hip_bfloat16* r1   = (__hip_bfloat16*)(w + P64);
  __hip_bfloat16* res  = (__hip_bfloat16*)(w + 2 * P64);   // conv2 out; out1 in-place; deform residual/src
  float* omb           = (float*)(w + 3 * P64);            // dedicated offset/mask buffer (15.9 MB < P64)
  __hip_bfloat16* cat  = (__hip_bfloat16*)(w + 4 * P64);
  char* tail = w + 4 * P64 + PCAT;
  short* wt1  = (short*)tail; tail += 73728;
  short* wt2c = (short*)tail; tail += 73728;
  short* wtf  = (short*)tail; tail += 73728;
  short* wtom = (short*)tail; tail += 73728;
  float* obb  = (float*)tail; tail += 128;
  short* wtb  = (short*)tail; tail += 73728;
  float* mean = (float*)tail; tail += 1024;
  __hip_bfloat16* fin = r1;         // overlay: fin reuses r1 slot (r1 dead after conv2)

  zb2_k<<<dim3(194, 4), 256, 0, stream>>>(xn, r1, res, cat);
  wts_k<<<dim3(144, 5), 256, 0, stream>>>(rw1, rw2, cw, offw, maskw, offb, maskb, dw,
                                          wt1, wt2c, wtf, wtom, obb, wtb, mean);
  cvt_k<<<dim3(576, 4, 3), 256, 0, stream>>>(x, inter, fea, xn, cat);

  conv_mfma_k<0, true , false><<<768, 256, 0, stream>>>(xn, wt1, rb1, r1, nullptr, nullptr);
  conv_mfma_k<0, false, true ><<<768, 256, 0, stream>>>(r1, wt2c, rb2, res, nullptr, mean);
  out1_k<<<4608, 256, 0, stream>>>(res, xn, mean, caw1, cab1, caw2, cab2);
  offmask_mfma_k<<<768, 256, 0, stream>>>(cat, wtom, obb, omb);
  deform_mfma_k<<<NB * 288, 512, 0, stream>>>(res, omb, wtb, fin);
  conv_mfma_k<1, false, false><<<768, 256, 0, stream>>>(fin, wtf, cb, nullptr, (float*)d_out, nullptr);
}

// Round 18
// 247.769 us; speedup vs baseline: 1.3804x; 1.0392x over previous
//
#include <hip/hip_runtime.h>
#include <hip/hip_bf16.h>
#include <hip/hip_fp16.h>
#include <math.h>

#define HSZ 192
#define WSZ 192
#define HWSZ (192*192)
#define PH 194                 // padded dim
#define PP (PH*PH)             // 37636 padded pixels
#define NB 4

typedef __attribute__((ext_vector_type(8))) short short8;
typedef __attribute__((ext_vector_type(4))) float f32x4;

__device__ inline unsigned short f2bf(float f) { __hip_bfloat16 h = __float2bfloat16(f); return *(unsigned short*)&h; }
__device__ inline float bf2f(__hip_bfloat16 h) { return __bfloat162float(h); }
__device__ inline float bflo(unsigned u) { return __uint_as_float(u << 16); }
__device__ inline float bfhi(unsigned u) { return __uint_as_float(u & 0xffff0000u); }

#define GLDS(SRC, DST) __builtin_amdgcn_global_load_lds( \
    (const __attribute__((address_space(1))) unsigned int*)(const void*)(SRC), \
    (__attribute__((address_space(3))) unsigned int*)(void*)(DST), 16, 0, 0)

#define MFMA(A,B,C) __builtin_amdgcn_mfma_f32_16x16x32_bf16((A),(B),(C),0,0,0)

// ------------- merged border-zero (4 buffers) -------------
__global__ void zb2_k(__hip_bfloat16* xn, __hip_bfloat16* r1, __hip_bfloat16* res,
                      __hip_bfloat16* cat) {
  int job = blockIdx.y;
  __hip_bfloat16* buf = job == 0 ? xn : job == 1 ? r1 : job == 2 ? res : cat;
  int Cn = (job == 3) ? 128 : 64;
  int cg8 = Cn >> 3;
  int tot = NB * 772 * cg8;
  int idx = blockIdx.x * 256 + threadIdx.x;
  if (idx >= tot) return;
  int cg = idx % cg8; int rem = idx / cg8;
  int e = rem % 772; int b = rem / 772;
  int h, w2;
  if (e < 194) { h = 0; w2 = e; }
  else if (e < 388) { h = 193; w2 = e - 194; }
  else if (e < 580) { h = e - 388 + 1; w2 = 0; }
  else { h = e - 580 + 1; w2 = 193; }
  uint4 z = make_uint4(0, 0, 0, 0);
  *(uint4*)&buf[(((size_t)b * PH + h) * PH + w2) * Cn + cg * 8] = z;
}

// ------------- merged weight prep (5 jobs) + mean zero -------------
__global__ void wts_k(const float* __restrict__ rw1, const float* __restrict__ rw2,
                      const float* __restrict__ cw, const float* __restrict__ offw,
                      const float* __restrict__ maskw, const float* __restrict__ offb,
                      const float* __restrict__ maskb, const float* __restrict__ dwv,
                      short* wt1, short* wt2c, short* wtf, short* wtom, float* ob,
                      short* wtb, float* meanz) {
  int job = blockIdx.y;
  int idx = blockIdx.x * 256 + threadIdx.x;   // < 36864
  if (job < 3) {
    const float* src = job == 0 ? rw1 : job == 1 ? rw2 : cw;
    short* dst = job == 0 ? wt1 : job == 1 ? wt2c : wtf;
    int kk = idx >> 12, rem = idx & 4095;
    int co = rem >> 6, ci = rem & 63;
    dst[idx] = (short)f2bf(src[(co * 64 + ci) * 9 + kk]);
  } else if (job == 3) {
    int kk = idx >> 12, rem = idx & 4095;
    int co = rem >> 7, ci = rem & 127;
    float v = 0.f;
    if (co < 18) v = offw[(co * 128 + ci) * 9 + kk];
    else if (co < 27) v = maskw[((co - 18) * 128 + ci) * 9 + kk];
    wtom[idx] = (short)f2bf(v);
    if (idx < 32) ob[idx] = idx < 18 ? offb[idx] : (idx < 27 ? maskb[idx - 18] : 0.f);
  } else {
    int o = idx / 576, rem = idx - o * 576;
    int kk = rem >> 6, ci = rem & 63;
    wtb[idx] = (short)f2bf(dwv[(o * 64 + ci) * 9 + kk]);
    if (blockIdx.x == 0 && threadIdx.x < 256) meanz[threadIdx.x] = 0.f;
  }
}

// ------------- merged NCHW f32 -> padded NHWC bf16 (x -> xn, inter/fea -> cat) -------------
__global__ __launch_bounds__(256) void cvt_k(const float* __restrict__ x,
    const float* __restrict__ inter, const float* __restrict__ fea,
    __hip_bfloat16* __restrict__ xn, __hip_bfloat16* __restrict__ cat) {
  int job = blockIdx.z;
  const float* src = job == 0 ? x : job == 1 ? inter : fea;
  __hip_bfloat16* dst = job == 0 ? xn : cat;
  int Cdst = job == 0 ? 64 : 128;
  int coff = job == 2 ? 64 : 0;
  __shared__ float s[64][65];
  int p0 = blockIdx.x * 64; int b = blockIdx.y;
  int lane = threadIdx.x & 63, g = threadIdx.x >> 6;
#pragma unroll
  for (int i = 0; i < 16; ++i) {
    int c = i * 4 + g;
    s[c][lane] = src[((size_t)b * 64 + c) * HWSZ + p0 + lane];
  }
  __syncthreads();
  int pix = threadIdx.x >> 2, cg = threadIdx.x & 3;
  int h = p0 / WSZ, w0 = p0 - h * WSZ + pix;
  size_t addr = (((size_t)b * PH + h + 1) * PH + 1 + w0) * Cdst + coff + cg * 16;
  unsigned pk2[8];
#pragma unroll
  for (int t = 0; t < 8; ++t)
    pk2[t] = (unsigned)f2bf(s[cg * 16 + 2 * t][pix]) | ((unsigned)f2bf(s[cg * 16 + 2 * t + 1][pix]) << 16);
  *(uint4*)&dst[addr]     = make_uint4(pk2[0], pk2[1], pk2[2], pk2[3]);
  *(uint4*)&dst[addr + 8] = make_uint4(pk2[4], pk2[5], pk2[6], pk2[7]);
}

// ------------- MFMA conv3x3 64->64: 512 threads, 8 waves (co split), row-dbuf staging -------------
// Each wave: 48 px (wid&3) x 32 co (wid>>2). 24 waves/CU at 3 blocks/CU.
template<int OUT_MODE, bool RELU, bool MEANACC>
__global__ __launch_bounds__(512, 3) void conv_mfma_k(
    const __hip_bfloat16* __restrict__ inp, const short* __restrict__ wt,
    const float* __restrict__ bias, __hip_bfloat16* __restrict__ outB,
    float* __restrict__ outF, float* __restrict__ meanout) {
  __shared__ __align__(16) short tbuf[2 * 12800];   // 2 row buffers x 25600 B
  __shared__ float smean[256];                       // 8 waves x 32 co
  int flat = ((int)blockIdx.x & 7) * 96 + ((int)blockIdx.x >> 3);
  const int b = flat / 192, h = flat - (flat / 192) * 192;
  const int tid = threadIdx.x, lane = tid & 63, wid = tid >> 6;   // wid 0..7
  const int q = lane >> 4, r16 = lane & 15;
  const int cw = wid >> 2;                 // co half (0/1)
  const int wm0 = (wid & 3) * 48;          // pixel group

  const __hip_bfloat16* base = inp + ((size_t)b * PH + h) * (PH * 64);
#define STAGE(BUF, R) do { \
    const char* gb_ = (const char*)(base + (size_t)(R) * (PH * 64)); \
    for (int s_ = wid; s_ < 25; s_ += 8) { \
      int pix_ = 8 * s_ + (lane >> 3); \
      const char* src_ = gb_ + pix_ * 128 + ((((lane & 7) ^ ((lane >> 3) & 7))) << 4); \
      GLDS(src_, tbuf + (BUF) * 12800 + s_ * 512); \
    } \
  } while (0)

  STAGE(0, 0);

  f32x4 acc[3][2];
  if (OUT_MODE == 0) {
#pragma unroll
    for (int nf = 0; nf < 2; ++nf) {
      float4 bv = *(const float4*)&bias[(cw * 2 + nf) * 16 + q * 4];
      f32x4 v; v[0] = bv.x; v[1] = bv.y; v[2] = bv.z; v[3] = bv.w;
      acc[0][nf] = v; acc[1][nf] = v; acc[2][nf] = v;
    }
  } else {
#pragma unroll
    for (int nf = 0; nf < 2; ++nf) {
      float bs = bias[(cw * 2 + nf) * 16 + r16];
      f32x4 v; v[0] = bs; v[1] = bs; v[2] = bs; v[3] = bs;
      acc[0][nf] = v; acc[1][nf] = v; acc[2][nf] = v;
    }
  }

  short8 bfr[2][2][2];                     // [buf][ciHalf][nf]
  {
    const short* wk0 = wt + r16 * 64 + q * 8;
#pragma unroll
    for (int nf = 0; nf < 2; ++nf) {
      bfr[0][0][nf] = *(const short8*)(wk0 + (cw * 2 + nf) * 1024);
      bfr[0][1][nf] = *(const short8*)(wk0 + (cw * 2 + nf) * 1024 + 32);
    }
  }
  __syncthreads();

#pragma unroll
  for (int ky = 0; ky < 3; ++ky) {
    const int cb = ky & 1;
    if (ky < 2) STAGE(cb ^ 1, ky + 1);
#pragma unroll
    for (int kx = 0; kx < 3; ++kx) {
      const int kk = ky * 3 + kx;
      const int cur = kk & 1;
      if (kk < 8) {
        const short* wk = wt + (kk + 1) * 4096 + r16 * 64 + q * 8;
#pragma unroll
        for (int nf = 0; nf < 2; ++nf) {
          bfr[cur ^ 1][0][nf] = *(const short8*)(wk + (cw * 2 + nf) * 1024);
          bfr[cur ^ 1][1][nf] = *(const short8*)(wk + (cw * 2 + nf) * 1024 + 32);
        }
      }
#pragma unroll
      for (int mf = 0; mf < 3; ++mf) {
        int pix = wm0 + mf * 16 + r16 + kx;
        const char* ab = (const char*)(tbuf + cb * 12800) + pix * 128;
        int sw = (pix & 7) << 4;
        short8 a0 = *(const short8*)(ab + ((q << 4) ^ sw));
        short8 a1 = *(const short8*)(ab + (((q + 4) << 4) ^ sw));
#pragma unroll
        for (int nf = 0; nf < 2; ++nf) {
          if (OUT_MODE == 0) {
            acc[mf][nf] = MFMA(bfr[cur][0][nf], a0, acc[mf][nf]);
            acc[mf][nf] = MFMA(bfr[cur][1][nf], a1, acc[mf][nf]);
          } else {
            acc[mf][nf] = MFMA(a0, bfr[cur][0][nf], acc[mf][nf]);
            acc[mf][nf] = MFMA(a1, bfr[cur][1][nf], acc[mf][nf]);
          }
        }
      }
    }
    __syncthreads();
  }
#undef STAGE

  if (MEANACC) {
    // swapped layout: col=pixel=r16, row=co_local = nf*16+q*4+rg (within co half cw)
    float t[2][4];
#pragma unroll
    for (int nf = 0; nf < 2; ++nf)
#pragma unroll
      for (int rg = 0; rg < 4; ++rg)
        t[nf][rg] = acc[0][nf][rg] + acc[1][nf][rg] + acc[2][nf][rg];
#pragma unroll
    for (int m = 1; m < 16; m <<= 1)
#pragma unroll
      for (int nf = 0; nf < 2; ++nf)
#pragma unroll
        for (int rg = 0; rg < 4; ++rg)
          t[nf][rg] += __shfl_xor(t[nf][rg], m);
    if (r16 == 0)
#pragma unroll
      for (int nf = 0; nf < 2; ++nf)
#pragma unroll
        for (int rg = 0; rg < 4; ++rg)
          smean[wid * 32 + nf * 16 + q * 4 + rg] = t[nf][rg];
    __syncthreads();
    if (tid < 64) {
      int half = tid >> 5, cl = tid & 31;
      atomicAdd(&meanout[b * 64 + tid],
                (smean[(half * 4 + 0) * 32 + cl] + smean[(half * 4 + 1) * 32 + cl] +
                 smean[(half * 4 + 2) * 32 + cl] + smean[(half * 4 + 3) * 32 + cl]) * (1.f / 36864.f));
    }
  }

  if (OUT_MODE == 0) {
    short* t1 = tbuf + 12800;
#pragma unroll
    for (int mf = 0; mf < 3; ++mf)
#pragma unroll
      for (int nf = 0; nf < 2; ++nf) {
        f32x4 v = acc[mf][nf];
        if (RELU) { v[0] = fmaxf(v[0], 0.f); v[1] = fmaxf(v[1], 0.f); v[2] = fmaxf(v[2], 0.f); v[3] = fmaxf(v[3], 0.f); }
        unsigned lo = (unsigned)f2bf(v[0]) | ((unsigned)f2bf(v[1]) << 16);
        unsigned hi = (unsigned)f2bf(v[2]) | ((unsigned)f2bf(v[3]) << 16);
        int pix = wm0 + mf * 16 + r16;
        int byteoff = (pix * 128 + (cw * 2 + nf) * 32 + q * 8) ^ ((pix & 7) << 4);
        *(uint2*)((char*)t1 + byteoff) = make_uint2(lo, hi);
      }
    __syncthreads();
    char* orow = (char*)outB + ((((size_t)b * PH + h + 1) * PH + 1) * 64) * 2;
    for (int s = wid; s < 24; s += 8) {
      int pix = 8 * s + (lane >> 3);
      int g16 = ((lane & 7) ^ (pix & 7)) << 4;
      uint4 d = *(const uint4*)((const char*)t1 + pix * 128 + g16);
      *(uint4*)(orow + pix * 128 + ((lane & 7) << 4)) = d;
    }
  } else {
    float* ob2 = outF + (size_t)b * 64 * HWSZ + h * WSZ;
#pragma unroll
    for (int mf = 0; mf < 3; ++mf)
#pragma unroll
      for (int nf = 0; nf < 2; ++nf) {
        int pix0 = wm0 + mf * 16 + q * 4;
        int co = (cw * 2 + nf) * 16 + r16;
        *(f32x4*)&ob2[(size_t)co * HWSZ + pix0] = acc[mf][nf];
      }
  }
}

// ------------- standalone offmask kernel (R14-validated, XCD-chunked vid) -------------
__global__ __launch_bounds__(256, 3) void offmask_mfma_k(
    const __hip_bfloat16* __restrict__ cat, const short* __restrict__ wt2,
    const float* __restrict__ ob, float* __restrict__ om) {
  int flat = ((int)blockIdx.x & 7) * 96 + ((int)blockIdx.x >> 3);
  const int b = flat / 192, h = flat - (flat / 192) * 192;
  const int tid = threadIdx.x, lane = tid & 63, wid = tid >> 6;
  const int q = lane >> 4, r16 = lane & 15;
  __shared__ __align__(16) short tile[200 * 128];      // 51200 B

  f32x4 acc[3][2];
#pragma unroll
  for (int nf = 0; nf < 2; ++nf) {
    float bs = ob[nf * 16 + r16];
    f32x4 v; v[0] = bs; v[1] = bs; v[2] = bs; v[3] = bs;
    acc[0][nf] = v; acc[1][nf] = v; acc[2][nf] = v;
  }
  const char* gb = (const char*)(cat + ((size_t)b * PH + h) * (PH * 128));
  const int wm0 = wid * 48;

  short8 bfr[2][4][2];
  {
    const short* wk0 = wt2 + r16 * 128 + q * 8;
#pragma unroll
    for (int c4 = 0; c4 < 4; ++c4) {
      bfr[0][c4][0] = *(const short8*)(wk0 + c4 * 32);
      bfr[0][c4][1] = *(const short8*)(wk0 + 2048 + c4 * 32);
    }
  }

#pragma unroll
  for (int r = 0; r < 3; ++r) {
    __syncthreads();
    for (int s = wid; s < 50; s += 4) {
      int pix = 4 * s + (lane >> 4);
      const char* src = gb + (size_t)r * (PH * 256) + pix * 256
                      + ((((lane & 15) ^ (pix & 15))) << 4);
      GLDS(src, tile + s * 512);
    }
    __syncthreads();
#pragma unroll
    for (int kx = 0; kx < 3; ++kx) {
      const int kk = r * 3 + kx;
      const int cur = kk & 1;
      if (kk < 8) {
        const short* wk = wt2 + (kk + 1) * 4096 + r16 * 128 + q * 8;
#pragma unroll
        for (int c4 = 0; c4 < 4; ++c4) {
          bfr[cur ^ 1][c4][0] = *(const short8*)(wk + c4 * 32);
          bfr[cur ^ 1][c4][1] = *(const short8*)(wk + 2048 + c4 * 32);
        }
      }
#pragma unroll
      for (int mf = 0; mf < 3; ++mf) {
        int pix = wm0 + mf * 16 + r16 + kx;
        const char* ab = (const char*)tile + pix * 256;
        int sw = (pix & 15) << 4;
        short8 a0 = *(const short8*)(ab + ((q << 4) ^ sw));
        short8 a1 = *(const short8*)(ab + (((4 + q) << 4) ^ sw));
        short8 a2 = *(const short8*)(ab + (((8 + q) << 4) ^ sw));
        short8 a3 = *(const short8*)(ab + (((12 + q) << 4) ^ sw));
        acc[mf][0] = MFMA(a0, bfr[cur][0][0], acc[mf][0]); acc[mf][1] = MFMA(a0, bfr[cur][0][1], acc[mf][1]);
        acc[mf][0] = MFMA(a1, bfr[cur][1][0], acc[mf][0]); acc[mf][1] = MFMA(a1, bfr[cur][1][1], acc[mf][1]);
        acc[mf][0] = MFMA(a2, bfr[cur][2][0], acc[mf][0]); acc[mf][1] = MFMA(a2, bfr[cur][2][1], acc[mf][1]);
        acc[mf][0] = MFMA(a3, bfr[cur][3][0], acc[mf][0]); acc[mf][1] = MFMA(a3, bfr[cur][3][1], acc[mf][1]);
      }
    }
  }
#pragma unroll
  for (int mf = 0; mf < 3; ++mf)
#pragma unroll
    for (int nf = 0; nf < 2; ++nf) {
      int co = nf * 16 + r16;
      if (co < 27) {
        f32x4 v = acc[mf][nf];
        if (co >= 18) {
          v[0] = 2.f / (1.f + expf(-v[0])); v[1] = 2.f / (1.f + expf(-v[1]));
          v[2] = 2.f / (1.f + expf(-v[2])); v[3] = 2.f / (1.f + expf(-v[3]));
        }
        *(f32x4*)&om[((size_t)(b * 27 + co)) * HWSZ + h * WSZ + wm0 + mf * 16 + q * 4] = v;
      }
    }
}

// ------------- out1 = res*sigmoid(CA(mean)) + x, IN-PLACE on res -------------
__global__ __launch_bounds__(256) void out1_k(__hip_bfloat16* __restrict__ res, const __hip_bfloat16* __restrict__ xn,
    const float* __restrict__ mean, const float* __restrict__ w1, const float* __restrict__ b1,
    const float* __restrict__ w2, const float* __restrict__ b2) {
  int idx = blockIdx.x * 256 + threadIdx.x;
  int b = idx / 294912; int rem = idx - b * 294912;
  int p = rem >> 3, c8 = rem & 7;
  int lane = threadIdx.x & 63, wid = threadIdx.x >> 6;

  __shared__ float s_t[4];
  {
    float prod = w1[wid * 64 + lane] * mean[b * 64 + lane];
#pragma unroll
    for (int m = 1; m < 64; m <<= 1) prod += __shfl_xor(prod, m);
    if (lane == 0) s_t[wid] = fmaxf(prod + b1[wid], 0.f);
  }
  __syncthreads();
  float t0 = s_t[0], t1 = s_t[1], t2 = s_t[2], t3 = s_t[3];

  int hh = p / WSZ, ww = p - hh * WSZ;
  size_t off = ((size_t)b * PP + (size_t)(hh + 1) * PH + ww + 1) * 64 + c8 * 8;
  __hip_bfloat16* rp = res + off;
  const __hip_bfloat16* xp = xn + off;
  unsigned pk[4];
#pragma unroll
  for (int t = 0; t < 4; ++t) {
    float y0, y1;
    {
      int c = c8 * 8 + 2 * t;
      const float4 wv0 = *(const float4*)&w2[c * 4];
      const float4 wv1 = *(const float4*)&w2[(c + 1) * 4];
      float v0 = b2[c]     + wv0.x * t0 + wv0.y * t1 + wv0.z * t2 + wv0.w * t3;
      float v1 = b2[c + 1] + wv1.x * t0 + wv1.y * t1 + wv1.z * t2 + wv1.w * t3;
      y0 = 1.f / (1.f + expf(-v0));
      y1 = 1.f / (1.f + expf(-v1));
    }
    float o0 = bf2f(rp[2 * t]) * y0 + bf2f(xp[2 * t]);
    float o1 = bf2f(rp[2 * t + 1]) * y1 + bf2f(xp[2 * t + 1]);
    pk[t] = (unsigned)f2bf(o0) | ((unsigned)f2bf(o1) << 16);
  }
  *(uint4*)rp = make_uint4(pk[0], pk[1], pk[2], pk[3]);
}

// ------------- deformable conv (R14 verbatim): 64 px/block, contiguous gathers, 2-set pipeline -------------
__global__ __launch_bounds__(256) void deform_mfma_k(
    const __hip_bfloat16* __restrict__ nhwc, const float* __restrict__ om,
    const short* __restrict__ wtb, __hip_bfloat16* __restrict__ fin) {
  // XCD-chunked swizzle: 2304 blocks, 8 XCDs, 288 contiguous per XCD
  int blk = ((int)blockIdx.x & 7) * 288 + ((int)blockIdx.x >> 3);
  int b = blk / 576;
  int p0 = (blk - b * 576) * 64;
  int tid = threadIdx.x, lane = tid & 63, wid = tid >> 6;
  int q = lane >> 4, r16 = lane & 15;
  __shared__ __align__(16) short sA[2][64][64];   // 2 x 8192 B slice buffers, rows 128 B XOR-swizzled
  __shared__ __half2 s_bw[2][9][64];
  __shared__ int s_pk[9][64];

  const float* omb = om + (size_t)b * 27 * HWSZ + p0;
  for (int e = tid; e < 576; e += 256) {
    int kk = e >> 6, pix = e & 63;
    int p = p0 + pix;
    int h = p / WSZ, w2 = p - h * WSZ;
    float oy = omb[(size_t)(2 * kk) * HWSZ + pix];
    float ox = omb[(size_t)(2 * kk + 1) * HWSZ + pix];
    float m2 = omb[(size_t)(18 + kk) * HWSZ + pix];
    float ys = (float)(h + kk / 3 - 1) + oy;
    float xs = (float)(w2 + kk % 3 - 1) + ox;
    float y0f = floorf(ys), x0f = floorf(xs);
    float wy1 = ys - y0f, wx1 = xs - x0f;
    float wy0 = 1.f - wy1, wx0 = 1.f - wx1;
    int y0 = (int)y0f, x0i = (int)x0f;
    int y1 = y0 + 1, x1 = x0i + 1;
    float vy0 = (y0 >= 0 && y0 < HSZ) ? 1.f : 0.f;
    float vx0 = (x0i >= 0 && x0i < WSZ) ? 1.f : 0.f;
    float vy1 = (y1 >= 0 && y1 < HSZ) ? 1.f : 0.f;
    float vx1 = (x1 >= 0 && x1 < WSZ) ? 1.f : 0.f;
    int y0c = min(max(y0, 0), HSZ - 1), x0c = min(max(x0i, 0), WSZ - 1);
    int y1c = min(max(y1, 0), HSZ - 1), x1c = min(max(x1, 0), WSZ - 1);
    s_bw[0][kk][pix] = __floats2half2_rn(wy0 * wx0 * m2 * vy0 * vx0, wy0 * wx1 * m2 * vy0 * vx1);
    s_bw[1][kk][pix] = __floats2half2_rn(wy1 * wx0 * m2 * vy1 * vx0, wy1 * wx1 * m2 * vy1 * vx1);
    s_pk[kk][pix] = ((((y0c + 1) * PH) + x0c + 1) << 2) | ((y1c - y0c) << 1) | (x1c - x0c);
  }
  __syncthreads();

  const __hip_bfloat16* nb = nhwc + (size_t)b * PP * 64;
  const int spix = tid >> 2, lg = tid & 3;
  const int rsw = (r16 & 7) << 4;

  uint4 Pa0, Pb0, Qa0, Qb0, Ra0, Rb0, Sa0, Sb0;
  uint4 Pa1, Pb1, Qa1, Qb1, Ra1, Rb1, Sa1, Sb1;
  float2 wab0, wcd0, wab1, wcd1;

#define ISSUE_R(KK, Pa,Pb,Qa,Qb,Ra,Rb,Sa,Sb, Wab, Wcd) do { \
    Wab = __half22float2(s_bw[0][KK][spix]); \
    Wcd = __half22float2(s_bw[1][KK][spix]); \
    int pk_ = s_pk[KK][spix]; \
    int i00_ = pk_ >> 2, dy_ = (pk_ >> 1) & 1, dx_ = pk_ & 1; \
    const __hip_bfloat16* g_ = nb + (size_t)i00_ * 64 + lg * 16; \
    Pa = *(const uint4*)g_;                     Pb = *(const uint4*)(g_ + 8); \
    Qa = *(const uint4*)(g_ + dx_ * 64);        Qb = *(const uint4*)(g_ + dx_ * 64 + 8); \
    Ra = *(const uint4*)(g_ + dy_ * (PH * 64)); Rb = *(const uint4*)(g_ + dy_ * (PH * 64) + 8); \
    Sa = *(const uint4*)(g_ + (dy_ * PH + dx_) * 64); Sb = *(const uint4*)(g_ + (dy_ * PH + dx_) * 64 + 8); \
  } while (0)
#define CMB(J, PA,QA,RA,SA, Wab, Wcd, OUT) do { \
    const unsigned* pa_ = (const unsigned*)&PA; const unsigned* qa_ = (const unsigned*)&QA; \
    const unsigned* ra_ = (const unsigned*)&RA; const unsigned* sa_ = (const unsigned*)&SA; \
    float lo_ = Wab.x * bflo(pa_[J]) + Wab.y * bflo(qa_[J]) + Wcd.x * bflo(ra_[J]) + Wcd.y * bflo(sa_[J]); \
    float hi_ = Wab.x * bfhi(pa_[J]) + Wab.y * bfhi(qa_[J]) + Wcd.x * bfhi(ra_[J]) + Wcd.y * bfhi(sa_[J]); \
    OUT = (unsigned)f2bf(lo_) | ((unsigned)f2bf(hi_) << 16); \
  } while (0)
#define CSTORE_R(BUFOFF, Pa,Pb,Qa,Qb,Ra,Rb,Sa,Sb, Wab, Wcd) do { \
    unsigned oa_[4], ob_[4]; \
    CMB(0, Pa,Qa,Ra,Sa, Wab, Wcd, oa_[0]); CMB(1, Pa,Qa,Ra,Sa, Wab, Wcd, oa_[1]); \
    CMB(2, Pa,Qa,Ra,Sa, Wab, Wcd, oa_[2]); CMB(3, Pa,Qa,Ra,Sa, Wab, Wcd, oa_[3]); \
    CMB(0, Pb,Qb,Rb,Sb, Wab, Wcd, ob_[0]); CMB(1, Pb,Qb,Rb,Sb, Wab, Wcd, ob_[1]); \
    CMB(2, Pb,Qb,Rb,Sb, Wab, Wcd, ob_[2]); CMB(3, Pb,Qb,Rb,Sb, Wab, Wcd, ob_[3]); \
    char* dst_ = (char*)sA + (BUFOFF) + spix * 128; \
    *(uint4*)(dst_ + ((((lg * 2) ^ (spix & 7))) << 4))     = make_uint4(oa_[0], oa_[1], oa_[2], oa_[3]); \
    *(uint4*)(dst_ + ((((lg * 2 + 1) ^ (spix & 7))) << 4)) = make_uint4(ob_[0], ob_[1], ob_[2], ob_[3]); \
  } while (0)

  ISSUE_R(0, Pa0,Pb0,Qa0,Qb0,Ra0,Rb0,Sa0,Sb0, wab0, wcd0);
  CSTORE_R(0, Pa0,Pb0,Qa0,Qb0,Ra0,Rb0,Sa0,Sb0, wab0, wcd0);
  ISSUE_R(1, Pa0,Pb0,Qa0,Qb0,Ra0,Rb0,Sa0,Sb0, wab0, wcd0);
  ISSUE_R(2, Pa1,Pb1,Qa1,Qb1,Ra1,Rb1,Sa1,Sb1, wab1, wcd1);

  f32x4 acc0 = (f32x4){0.f, 0.f, 0.f, 0.f};
  f32x4 acc1 = (f32x4){0.f, 0.f, 0.f, 0.f};
  f32x4 acc2 = (f32x4){0.f, 0.f, 0.f, 0.f};
  f32x4 acc3 = (f32x4){0.f, 0.f, 0.f, 0.f};
  const short* wrow = wtb + (size_t)(wid * 16 + r16) * 576;
  const char* a0base = (const char*)sA + r16 * 128;
  const char* a1base = (const char*)sA + (r16 + 16) * 128;
  const char* a2base = (const char*)sA + (r16 + 32) * 128;
  const char* a3base = (const char*)sA + (r16 + 48) * 128;

#pragma unroll
  for (int kk = 0; kk < 9; ++kk) {
    const int bo = (kk & 1) * 8192;
    __syncthreads();
#pragma unroll
    for (int s = 0; s < 2; ++s) {
      short8 wf = *(const short8*)(wrow + kk * 64 + s * 32 + q * 8);
      int off = bo + ((s * 64 + q * 16) ^ rsw);
      acc0 = MFMA(wf, *(const short8*)(a0base + off), acc0);
      acc1 = MFMA(wf, *(const short8*)(a1base + off), acc1);
      acc2 = MFMA(wf, *(const short8*)(a2base + off), acc2);
      acc3 = MFMA(wf, *(const short8*)(a3base + off), acc3);
    }
    if (kk < 8) {
      const int nbo = ((kk + 1) & 1) * 8192;
      if ((kk & 1) == 0) {
        CSTORE_R(nbo, Pa0,Pb0,Qa0,Qb0,Ra0,Rb0,Sa0,Sb0, wab0, wcd0);
        if (kk + 3 <= 8) ISSUE_R(kk + 3, Pa0,Pb0,Qa0,Qb0,Ra0,Rb0,Sa0,Sb0, wab0, wcd0);
      } else {
        CSTORE_R(nbo, Pa1,Pb1,Qa1,Qb1,Ra1,Rb1,Sa1,Sb1, wab1, wcd1);
        if (kk + 3 <= 8) ISSUE_R(kk + 3, Pa1,Pb1,Qa1,Qb1,Ra1,Rb1,Sa1,Sb1, wab1, wcd1);
      }
    }
  }

  // epilogue: +out1 residual (64-px blocks never cross rows: 192 = 3*64)
  int h0 = p0 / WSZ, w0 = p0 - h0 * WSZ;
  size_t ro = ((size_t)(h0 + 1) * PH + w0 + 1) * 64;
  const __hip_bfloat16* resid = nb + ro;
  __hip_bfloat16* fp = fin + (size_t)b * PP * 64 + ro;
#pragma unroll
  for (int nf = 0; nf < 4; ++nf) {
    f32x4 av = nf == 0 ? acc0 : nf == 1 ? acc1 : nf == 2 ? acc2 : acc3;
    int pix = r16 + nf * 16;
    int co = wid * 16 + q * 4;
    const unsigned* rr = (const unsigned*)(resid + (size_t)pix * 64 + co);
    unsigned r0 = rr[0], r1 = rr[1];
    float o0 = av[0] + bflo(r0);
    float o1 = av[1] + bfhi(r0);
    float o2 = av[2] + bflo(r1);
    float o3 = av[3] + bfhi(r1);
    uint2 pk2 = make_uint2((unsigned)f2bf(o0) | ((unsigned)f2bf(o1) << 16),
                           (unsigned)f2bf(o2) | ((unsigned)f2bf(o3) << 16));
    *(uint2*)(fp + (size_t)pix * 64 + co) = pk2;
  }
#undef ISSUE_R
#undef CMB
#undef CSTORE_R
}

extern "C" void kernel_launch(void* const* d_in, const int* in_sizes, int n_in,
                              void* d_out, int out_size, void* d_ws, size_t ws_size,
                              hipStream_t stream) {
  (void)in_sizes; (void)n_in; (void)out_size; (void)ws_size;
  const float* x     = (const float*)d_in[0];
  const float* inter = (const float*)d_in[1];
  const float* fea   = (const float*)d_in[2];
  const float* rw1   = (const float*)d_in[3];
  const float* rb1   = (const float*)d_in[4];
  const float* rw2   = (const float*)d_in[5];
  const float* rb2   = (const float*)d_in[6];
  const float* caw1  = (const float*)d_in[7];
  const float* cab1  = (const float*)d_in[8];
  const float* caw2  = (const float*)d_in[9];
  const float* cab2  = (const float*)d_in[10];
  const float* offw  = (const float*)d_in[11];
  const float* offb  = (const float*)d_in[12];
  const float* maskw = (const float*)d_in[13];
  const float* maskb = (const float*)d_in[14];
  const float* dw    = (const float*)d_in[15];
  const float* cw    = (const float*)d_in[16];
  const float* cb    = (const float*)d_in[17];

  char* w = (char*)d_ws;
  const size_t P64 = (size_t)NB * PP * 64 * 2 + 4096;
  const size_t PCAT = (size_t)NB * PP * 128 * 2 + 4096;
  __hip_bfloat16* xn   = (__hip_bfloat16*)(w);
  __hip_bfloat16* r1   = (__hip_bfloat16*)(w + P64);
  __hip_bfloat16* res  = (__hip_bfloat16*)(w + 2 * P64);   // conv2 out; out1 in-place; deform residual/src
  float* omb           = (float*)(w + 3 * P64);            // dedicated offset/mask buffer (15.9 MB < P64)
  __hip_bfloat16* cat  = (__hip_bfloat16*)(w + 4 * P64);
  char* tail = w + 4 * P64 + PCAT;
  short* wt1  = (short*)tail; tail += 73728;
  short* wt2c = (short*)tail; tail += 73728;
  short* wtf  = (short*)tail; tail += 73728;
  short* wtom = (short*)tail; tail += 73728;
  float* obb  = (float*)tail; tail += 128;
  short* wtb  = (short*)tail; tail += 73728;
  float* mean = (float*)tail; tail += 1024;
  __hip_bfloat16* fin = r1;         // overlay: fin reuses r1 slot (r1 dead after conv2)

  zb2_k<<<dim3(194, 4), 256, 0, stream>>>(xn, r1, res, cat);
  wts_k<<<dim3(144, 5), 256, 0, stream>>>(rw1, rw2, cw, offw, maskw, offb, maskb, dw,
                                          wt1, wt2c, wtf, wtom, obb, wtb, mean);
  cvt_k<<<dim3(576, 4, 3), 256, 0, stream>>>(x, inter, fea, xn, cat);

  conv_mfma_k<0, true , false><<<768, 512, 0, stream>>>(xn, wt1, rb1, r1, nullptr, nullptr);
  conv_mfma_k<0, false, true ><<<768, 512, 0, stream>>>(r1, wt2c, rb2, res, nullptr, mean);
  out1_k<<<4608, 256, 0, stream>>>(res, xn, mean, caw1, cab1, caw2, cab2);
  offmask_mfma_k<<<768, 256, 0, stream>>>(cat, wtom, obb, omb);
  deform_mfma_k<<<NB * 576, 256, 0, stream>>>(res, omb, wtb, fin);
  conv_mfma_k<1, false, false><<<768, 512, 0, stream>>>(fin, wtf, cb, nullptr, (float*)d_out, nullptr);
}

// Round 19
// 247.202 us; speedup vs baseline: 1.3836x; 1.0023x over previous
//
#include <hip/hip_runtime.h>
#include <hip/hip_bf16.h>
#include <hip/hip_fp16.h>
#include <math.h>

#define HSZ 192
#define WSZ 192
#define HWSZ (192*192)
#define PH 194                 // padded dim
#define PP (PH*PH)             // 37636 padded pixels
#define NB 4

typedef __attribute__((ext_vector_type(8))) short short8;
typedef __attribute__((ext_vector_type(4))) float f32x4;

__device__ inline unsigned short f2bf(float f) { __hip_bfloat16 h = __float2bfloat16(f); return *(unsigned short*)&h; }
__device__ inline float bf2f(__hip_bfloat16 h) { return __bfloat162float(h); }
__device__ inline float bflo(unsigned u) { return __uint_as_float(u << 16); }
__device__ inline float bfhi(unsigned u) { return __uint_as_float(u & 0xffff0000u); }

#define GLDS(SRC, DST) __builtin_amdgcn_global_load_lds( \
    (const __attribute__((address_space(1))) unsigned int*)(const void*)(SRC), \
    (__attribute__((address_space(3))) unsigned int*)(void*)(DST), 16, 0, 0)

#define MFMA(A,B,C) __builtin_amdgcn_mfma_f32_16x16x32_bf16((A),(B),(C),0,0,0)

// ------------- merged border-zero (4 buffers) -------------
__global__ void zb2_k(__hip_bfloat16* xn, __hip_bfloat16* r1, __hip_bfloat16* res,
                      __hip_bfloat16* cat) {
  int job = blockIdx.y;
  __hip_bfloat16* buf = job == 0 ? xn : job == 1 ? r1 : job == 2 ? res : cat;
  int Cn = (job == 3) ? 128 : 64;
  int cg8 = Cn >> 3;
  int tot = NB * 772 * cg8;
  int idx = blockIdx.x * 256 + threadIdx.x;
  if (idx >= tot) return;
  int cg = idx % cg8; int rem = idx / cg8;
  int e = rem % 772; int b = rem / 772;
  int h, w2;
  if (e < 194) { h = 0; w2 = e; }
  else if (e < 388) { h = 193; w2 = e - 194; }
  else if (e < 580) { h = e - 388 + 1; w2 = 0; }
  else { h = e - 580 + 1; w2 = 193; }
  uint4 z = make_uint4(0, 0, 0, 0);
  *(uint4*)&buf[(((size_t)b * PH + h) * PH + w2) * Cn + cg * 8] = z;
}

// ------------- merged weight prep (5 jobs) + mean zero -------------
__global__ void wts_k(const float* __restrict__ rw1, const float* __restrict__ rw2,
                      const float* __restrict__ cw, const float* __restrict__ offw,
                      const float* __restrict__ maskw, const float* __restrict__ offb,
                      const float* __restrict__ maskb, const float* __restrict__ dwv,
                      short* wt1, short* wt2c, short* wtf, short* wtom, float* ob,
                      short* wtb, float* meanz) {
  int job = blockIdx.y;
  int idx = blockIdx.x * 256 + threadIdx.x;   // < 36864
  if (job < 3) {
    const float* src = job == 0 ? rw1 : job == 1 ? rw2 : cw;
    short* dst = job == 0 ? wt1 : job == 1 ? wt2c : wtf;
    int kk = idx >> 12, rem = idx & 4095;
    int co = rem >> 6, ci = rem & 63;
    dst[idx] = (short)f2bf(src[(co * 64 + ci) * 9 + kk]);
  } else if (job == 3) {
    int kk = idx >> 12, rem = idx & 4095;
    int co = rem >> 7, ci = rem & 127;
    float v = 0.f;
    if (co < 18) v = offw[(co * 128 + ci) * 9 + kk];
    else if (co < 27) v = maskw[((co - 18) * 128 + ci) * 9 + kk];
    wtom[idx] = (short)f2bf(v);
    if (idx < 32) ob[idx] = idx < 18 ? offb[idx] : (idx < 27 ? maskb[idx - 18] : 0.f);
  } else {
    int o = idx / 576, rem = idx - o * 576;
    int kk = rem >> 6, ci = rem & 63;
    wtb[idx] = (short)f2bf(dwv[(o * 64 + ci) * 9 + kk]);
    if (blockIdx.x == 0 && threadIdx.x < 256) meanz[threadIdx.x] = 0.f;
  }
}

// ------------- merged NCHW f32 -> padded NHWC bf16 (x -> xn, inter/fea -> cat) -------------
__global__ __launch_bounds__(256) void cvt_k(const float* __restrict__ x,
    const float* __restrict__ inter, const float* __restrict__ fea,
    __hip_bfloat16* __restrict__ xn, __hip_bfloat16* __restrict__ cat) {
  int job = blockIdx.z;
  const float* src = job == 0 ? x : job == 1 ? inter : fea;
  __hip_bfloat16* dst = job == 0 ? xn : cat;
  int Cdst = job == 0 ? 64 : 128;
  int coff = job == 2 ? 64 : 0;
  __shared__ float s[64][65];
  int p0 = blockIdx.x * 64; int b = blockIdx.y;
  int lane = threadIdx.x & 63, g = threadIdx.x >> 6;
#pragma unroll
  for (int i = 0; i < 16; ++i) {
    int c = i * 4 + g;
    s[c][lane] = src[((size_t)b * 64 + c) * HWSZ + p0 + lane];
  }
  __syncthreads();
  int pix = threadIdx.x >> 2, cg = threadIdx.x & 3;
  int h = p0 / WSZ, w0 = p0 - h * WSZ + pix;
  size_t addr = (((size_t)b * PH + h + 1) * PH + 1 + w0) * Cdst + coff + cg * 16;
  unsigned pk2[8];
#pragma unroll
  for (int t = 0; t < 8; ++t)
    pk2[t] = (unsigned)f2bf(s[cg * 16 + 2 * t][pix]) | ((unsigned)f2bf(s[cg * 16 + 2 * t + 1][pix]) << 16);
  *(uint4*)&dst[addr]     = make_uint4(pk2[0], pk2[1], pk2[2], pk2[3]);
  *(uint4*)&dst[addr + 8] = make_uint4(pk2[4], pk2[5], pk2[6], pk2[7]);
}

// ------------- MFMA conv3x3 64->64: 512 threads, 8 waves (co split), row-dbuf staging -------------
template<int OUT_MODE, bool RELU, bool MEANACC>
__global__ __launch_bounds__(512, 3) void conv_mfma_k(
    const __hip_bfloat16* __restrict__ inp, const short* __restrict__ wt,
    const float* __restrict__ bias, __hip_bfloat16* __restrict__ outB,
    float* __restrict__ outF, float* __restrict__ meanout) {
  __shared__ __align__(16) short tbuf[2 * 12800];   // 2 row buffers x 25600 B
  __shared__ float smean[256];                       // 8 waves x 32 co
  int flat = ((int)blockIdx.x & 7) * 96 + ((int)blockIdx.x >> 3);
  const int b = flat / 192, h = flat - (flat / 192) * 192;
  const int tid = threadIdx.x, lane = tid & 63, wid = tid >> 6;   // wid 0..7
  const int q = lane >> 4, r16 = lane & 15;
  const int cw = wid >> 2;                 // co half (0/1)
  const int wm0 = (wid & 3) * 48;          // pixel group

  const __hip_bfloat16* base = inp + ((size_t)b * PH + h) * (PH * 64);
#define STAGE(BUF, R) do { \
    const char* gb_ = (const char*)(base + (size_t)(R) * (PH * 64)); \
    for (int s_ = wid; s_ < 25; s_ += 8) { \
      int pix_ = 8 * s_ + (lane >> 3); \
      const char* src_ = gb_ + pix_ * 128 + ((((lane & 7) ^ ((lane >> 3) & 7))) << 4); \
      GLDS(src_, tbuf + (BUF) * 12800 + s_ * 512); \
    } \
  } while (0)

  STAGE(0, 0);

  f32x4 acc[3][2];
  if (OUT_MODE == 0) {
#pragma unroll
    for (int nf = 0; nf < 2; ++nf) {
      float4 bv = *(const float4*)&bias[(cw * 2 + nf) * 16 + q * 4];
      f32x4 v; v[0] = bv.x; v[1] = bv.y; v[2] = bv.z; v[3] = bv.w;
      acc[0][nf] = v; acc[1][nf] = v; acc[2][nf] = v;
    }
  } else {
#pragma unroll
    for (int nf = 0; nf < 2; ++nf) {
      float bs = bias[(cw * 2 + nf) * 16 + r16];
      f32x4 v; v[0] = bs; v[1] = bs; v[2] = bs; v[3] = bs;
      acc[0][nf] = v; acc[1][nf] = v; acc[2][nf] = v;
    }
  }

  short8 bfr[2][2][2];                     // [buf][ciHalf][nf]
  {
    const short* wk0 = wt + r16 * 64 + q * 8;
#pragma unroll
    for (int nf = 0; nf < 2; ++nf) {
      bfr[0][0][nf] = *(const short8*)(wk0 + (cw * 2 + nf) * 1024);
      bfr[0][1][nf] = *(const short8*)(wk0 + (cw * 2 + nf) * 1024 + 32);
    }
  }
  __syncthreads();

#pragma unroll
  for (int ky = 0; ky < 3; ++ky) {
    const int cb = ky & 1;
    if (ky < 2) STAGE(cb ^ 1, ky + 1);
#pragma unroll
    for (int kx = 0; kx < 3; ++kx) {
      const int kk = ky * 3 + kx;
      const int cur = kk & 1;
      if (kk < 8) {
        const short* wk = wt + (kk + 1) * 4096 + r16 * 64 + q * 8;
#pragma unroll
        for (int nf = 0; nf < 2; ++nf) {
          bfr[cur ^ 1][0][nf] = *(const short8*)(wk + (cw * 2 + nf) * 1024);
          bfr[cur ^ 1][1][nf] = *(const short8*)(wk + (cw * 2 + nf) * 1024 + 32);
        }
      }
#pragma unroll
      for (int mf = 0; mf < 3; ++mf) {
        int pix = wm0 + mf * 16 + r16 + kx;
        const char* ab = (const char*)(tbuf + cb * 12800) + pix * 128;
        int sw = (pix & 7) << 4;
        short8 a0 = *(const short8*)(ab + ((q << 4) ^ sw));
        short8 a1 = *(const short8*)(ab + (((q + 4) << 4) ^ sw));
#pragma unroll
        for (int nf = 0; nf < 2; ++nf) {
          if (OUT_MODE == 0) {
            acc[mf][nf] = MFMA(bfr[cur][0][nf], a0, acc[mf][nf]);
            acc[mf][nf] = MFMA(bfr[cur][1][nf], a1, acc[mf][nf]);
          } else {
            acc[mf][nf] = MFMA(a0, bfr[cur][0][nf], acc[mf][nf]);
            acc[mf][nf] = MFMA(a1, bfr[cur][1][nf], acc[mf][nf]);
          }
        }
      }
    }
    __syncthreads();
  }
#undef STAGE

  if (MEANACC) {
    float t[2][4];
#pragma unroll
    for (int nf = 0; nf < 2; ++nf)
#pragma unroll
      for (int rg = 0; rg < 4; ++rg)
        t[nf][rg] = acc[0][nf][rg] + acc[1][nf][rg] + acc[2][nf][rg];
#pragma unroll
    for (int m = 1; m < 16; m <<= 1)
#pragma unroll
      for (int nf = 0; nf < 2; ++nf)
#pragma unroll
        for (int rg = 0; rg < 4; ++rg)
          t[nf][rg] += __shfl_xor(t[nf][rg], m);
    if (r16 == 0)
#pragma unroll
      for (int nf = 0; nf < 2; ++nf)
#pragma unroll
        for (int rg = 0; rg < 4; ++rg)
          smean[wid * 32 + nf * 16 + q * 4 + rg] = t[nf][rg];
    __syncthreads();
    if (tid < 64) {
      int half = tid >> 5, cl = tid & 31;
      atomicAdd(&meanout[b * 64 + tid],
                (smean[(half * 4 + 0) * 32 + cl] + smean[(half * 4 + 1) * 32 + cl] +
                 smean[(half * 4 + 2) * 32 + cl] + smean[(half * 4 + 3) * 32 + cl]) * (1.f / 36864.f));
    }
  }

  if (OUT_MODE == 0) {
    short* t1 = tbuf + 12800;
#pragma unroll
    for (int mf = 0; mf < 3; ++mf)
#pragma unroll
      for (int nf = 0; nf < 2; ++nf) {
        f32x4 v = acc[mf][nf];
        if (RELU) { v[0] = fmaxf(v[0], 0.f); v[1] = fmaxf(v[1], 0.f); v[2] = fmaxf(v[2], 0.f); v[3] = fmaxf(v[3], 0.f); }
        unsigned lo = (unsigned)f2bf(v[0]) | ((unsigned)f2bf(v[1]) << 16);
        unsigned hi = (unsigned)f2bf(v[2]) | ((unsigned)f2bf(v[3]) << 16);
        int pix = wm0 + mf * 16 + r16;
        int byteoff = (pix * 128 + (cw * 2 + nf) * 32 + q * 8) ^ ((pix & 7) << 4);
        *(uint2*)((char*)t1 + byteoff) = make_uint2(lo, hi);
      }
    __syncthreads();
    char* orow = (char*)outB + ((((size_t)b * PH + h + 1) * PH + 1) * 64) * 2;
    for (int s = wid; s < 24; s += 8) {
      int pix = 8 * s + (lane >> 3);
      int g16 = ((lane & 7) ^ (pix & 7)) << 4;
      uint4 d = *(const uint4*)((const char*)t1 + pix * 128 + g16);
      *(uint4*)(orow + pix * 128 + ((lane & 7) << 4)) = d;
    }
  } else {
    float* ob2 = outF + (size_t)b * 64 * HWSZ + h * WSZ;
#pragma unroll
    for (int mf = 0; mf < 3; ++mf)
#pragma unroll
      for (int nf = 0; nf < 2; ++nf) {
        int pix0 = wm0 + mf * 16 + q * 4;
        int co = (cw * 2 + nf) * 16 + r16;
        *(f32x4*)&ob2[(size_t)co * HWSZ + pix0] = acc[mf][nf];
      }
  }
}

// ------------- offmask: 512 threads, 8 waves (48 px x 16 co each), row staging -------------
__global__ __launch_bounds__(512, 3) void offmask_mfma_k(
    const __hip_bfloat16* __restrict__ cat, const short* __restrict__ wt2,
    const float* __restrict__ ob, float* __restrict__ om) {
  int flat = ((int)blockIdx.x & 7) * 96 + ((int)blockIdx.x >> 3);
  const int b = flat / 192, h = flat - (flat / 192) * 192;
  const int tid = threadIdx.x, lane = tid & 63, wid = tid >> 6;   // wid 0..7
  const int q = lane >> 4, r16 = lane & 15;
  const int cw = wid >> 2;                 // co half: 0 -> co 0..15, 1 -> co 16..31
  const int wm0 = (wid & 3) * 48;          // pixel group
  __shared__ __align__(16) short tile[200 * 128];      // 51200 B

  f32x4 acc[3];
  {
    float bs = ob[cw * 16 + r16];
    f32x4 v; v[0] = bs; v[1] = bs; v[2] = bs; v[3] = bs;
    acc[0] = v; acc[1] = v; acc[2] = v;
  }
  const char* gb = (const char*)(cat + ((size_t)b * PH + h) * (PH * 128));

  short8 bfr[2][4];                        // [buf][ci quarter]
  {
    const short* wk0 = wt2 + cw * 2048 + r16 * 128 + q * 8;
#pragma unroll
    for (int c4 = 0; c4 < 4; ++c4)
      bfr[0][c4] = *(const short8*)(wk0 + c4 * 32);
  }

#pragma unroll
  for (int r = 0; r < 3; ++r) {
    __syncthreads();
    for (int s = wid; s < 50; s += 8) {
      int pix = 4 * s + (lane >> 4);
      const char* src = gb + (size_t)r * (PH * 256) + pix * 256
                      + ((((lane & 15) ^ (pix & 15))) << 4);
      GLDS(src, tile + s * 512);
    }
    __syncthreads();
#pragma unroll
    for (int kx = 0; kx < 3; ++kx) {
      const int kk = r * 3 + kx;
      const int cur = kk & 1;
      if (kk < 8) {
        const short* wk = wt2 + (kk + 1) * 4096 + cw * 2048 + r16 * 128 + q * 8;
#pragma unroll
        for (int c4 = 0; c4 < 4; ++c4)
          bfr[cur ^ 1][c4] = *(const short8*)(wk + c4 * 32);
      }
#pragma unroll
      for (int mf = 0; mf < 3; ++mf) {
        int pix = wm0 + mf * 16 + r16 + kx;
        const char* ab = (const char*)tile + pix * 256;
        int sw = (pix & 15) << 4;
        short8 a0 = *(const short8*)(ab + ((q << 4) ^ sw));
        short8 a1 = *(const short8*)(ab + (((4 + q) << 4) ^ sw));
        short8 a2 = *(const short8*)(ab + (((8 + q) << 4) ^ sw));
        short8 a3 = *(const short8*)(ab + (((12 + q) << 4) ^ sw));
        acc[mf] = MFMA(a0, bfr[cur][0], acc[mf]);
        acc[mf] = MFMA(a1, bfr[cur][1], acc[mf]);
        acc[mf] = MFMA(a2, bfr[cur][2], acc[mf]);
        acc[mf] = MFMA(a3, bfr[cur][3], acc[mf]);
      }
    }
  }
  int co = cw * 16 + r16;
  if (co < 27) {
#pragma unroll
    for (int mf = 0; mf < 3; ++mf) {
      f32x4 v = acc[mf];
      if (co >= 18) {
        v[0] = 2.f / (1.f + expf(-v[0])); v[1] = 2.f / (1.f + expf(-v[1]));
        v[2] = 2.f / (1.f + expf(-v[2])); v[3] = 2.f / (1.f + expf(-v[3]));
      }
      *(f32x4*)&om[((size_t)(b * 27 + co)) * HWSZ + h * WSZ + wm0 + mf * 16 + q * 4] = v;
    }
  }
}

// ------------- out1 = res*sigmoid(CA(mean)) + x, IN-PLACE on res -------------
__global__ __launch_bounds__(256) void out1_k(__hip_bfloat16* __restrict__ res, const __hip_bfloat16* __restrict__ xn,
    const float* __restrict__ mean, const float* __restrict__ w1, const float* __restrict__ b1,
    const float* __restrict__ w2, const float* __restrict__ b2) {
  int idx = blockIdx.x * 256 + threadIdx.x;
  int b = idx / 294912; int rem = idx - b * 294912;
  int p = rem >> 3, c8 = rem & 7;
  int lane = threadIdx.x & 63, wid = threadIdx.x >> 6;

  __shared__ float s_t[4];
  {
    float prod = w1[wid * 64 + lane] * mean[b * 64 + lane];
#pragma unroll
    for (int m = 1; m < 64; m <<= 1) prod += __shfl_xor(prod, m);
    if (lane == 0) s_t[wid] = fmaxf(prod + b1[wid], 0.f);
  }
  __syncthreads();
  float t0 = s_t[0], t1 = s_t[1], t2 = s_t[2], t3 = s_t[3];

  int hh = p / WSZ, ww = p - hh * WSZ;
  size_t off = ((size_t)b * PP + (size_t)(hh + 1) * PH + ww + 1) * 64 + c8 * 8;
  __hip_bfloat16* rp = res + off;
  const __hip_bfloat16* xp = xn + off;
  unsigned pk[4];
#pragma unroll
  for (int t = 0; t < 4; ++t) {
    float y0, y1;
    {
      int c = c8 * 8 + 2 * t;
      const float4 wv0 = *(const float4*)&w2[c * 4];
      const float4 wv1 = *(const float4*)&w2[(c + 1) * 4];
      float v0 = b2[c]     + wv0.x * t0 + wv0.y * t1 + wv0.z * t2 + wv0.w * t3;
      float v1 = b2[c + 1] + wv1.x * t0 + wv1.y * t1 + wv1.z * t2 + wv1.w * t3;
      y0 = 1.f / (1.f + expf(-v0));
      y1 = 1.f / (1.f + expf(-v1));
    }
    float o0 = bf2f(rp[2 * t]) * y0 + bf2f(xp[2 * t]);
    float o1 = bf2f(rp[2 * t + 1]) * y1 + bf2f(xp[2 * t + 1]);
    pk[t] = (unsigned)f2bf(o0) | ((unsigned)f2bf(o1) << 16);
  }
  *(uint4*)rp = make_uint4(pk[0], pk[1], pk[2], pk[3]);
}

// ------------- deformable conv (R14 verbatim): 64 px/block, contiguous gathers, 2-set pipeline -------------
__global__ __launch_bounds__(256) void deform_mfma_k(
    const __hip_bfloat16* __restrict__ nhwc, const float* __restrict__ om,
    const short* __restrict__ wtb, __hip_bfloat16* __restrict__ fin) {
  // XCD-chunked swizzle: 2304 blocks, 8 XCDs, 288 contiguous per XCD
  int blk = ((int)blockIdx.x & 7) * 288 + ((int)blockIdx.x >> 3);
  int b = blk / 576;
  int p0 = (blk - b * 576) * 64;
  int tid = threadIdx.x, lane = tid & 63, wid = tid >> 6;
  int q = lane >> 4, r16 = lane & 15;
  __shared__ __align__(16) short sA[2][64][64];   // 2 x 8192 B slice buffers, rows 128 B XOR-swizzled
  __shared__ __half2 s_bw[2][9][64];
  __shared__ int s_pk[9][64];

  const float* omb = om + (size_t)b * 27 * HWSZ + p0;
  for (int e = tid; e < 576; e += 256) {
    int kk = e >> 6, pix = e & 63;
    int p = p0 + pix;
    int h = p / WSZ, w2 = p - h * WSZ;
    float oy = omb[(size_t)(2 * kk) * HWSZ + pix];
    float ox = omb[(size_t)(2 * kk + 1) * HWSZ + pix];
    float m2 = omb[(size_t)(18 + kk) * HWSZ + pix];
    float ys = (float)(h + kk / 3 - 1) + oy;
    float xs = (float)(w2 + kk % 3 - 1) + ox;
    float y0f = floorf(ys), x0f = floorf(xs);
    float wy1 = ys - y0f, wx1 = xs - x0f;
    float wy0 = 1.f - wy1, wx0 = 1.f - wx1;
    int y0 = (int)y0f, x0i = (int)x0f;
    int y1 = y0 + 1, x1 = x0i + 1;
    float vy0 = (y0 >= 0 && y0 < HSZ) ? 1.f : 0.f;
    float vx0 = (x0i >= 0 && x0i < WSZ) ? 1.f : 0.f;
    float vy1 = (y1 >= 0 && y1 < HSZ) ? 1.f : 0.f;
    float vx1 = (x1 >= 0 && x1 < WSZ) ? 1.f : 0.f;
    int y0c = min(max(y0, 0), HSZ - 1), x0c = min(max(x0i, 0), WSZ - 1);
    int y1c = min(max(y1, 0), HSZ - 1), x1c = min(max(x1, 0), WSZ - 1);
    s_bw[0][kk][pix] = __floats2half2_rn(wy0 * wx0 * m2 * vy0 * vx0, wy0 * wx1 * m2 * vy0 * vx1);
    s_bw[1][kk][pix] = __floats2half2_rn(wy1 * wx0 * m2 * vy1 * vx0, wy1 * wx1 * m2 * vy1 * vx1);
    s_pk[kk][pix] = ((((y0c + 1) * PH) + x0c + 1) << 2) | ((y1c - y0c) << 1) | (x1c - x0c);
  }
  __syncthreads();

  const __hip_bfloat16* nb = nhwc + (size_t)b * PP * 64;
  const int spix = tid >> 2, lg = tid & 3;
  const int rsw = (r16 & 7) << 4;

  uint4 Pa0, Pb0, Qa0, Qb0, Ra0, Rb0, Sa0, Sb0;
  uint4 Pa1, Pb1, Qa1, Qb1, Ra1, Rb1, Sa1, Sb1;
  float2 wab0, wcd0, wab1, wcd1;

#define ISSUE_R(KK, Pa,Pb,Qa,Qb,Ra,Rb,Sa,Sb, Wab, Wcd) do { \
    Wab = __half22float2(s_bw[0][KK][spix]); \
    Wcd = __half22float2(s_bw[1][KK][spix]); \
    int pk_ = s_pk[KK][spix]; \
    int i00_ = pk_ >> 2, dy_ = (pk_ >> 1) & 1, dx_ = pk_ & 1; \
    const __hip_bfloat16* g_ = nb + (size_t)i00_ * 64 + lg * 16; \
    Pa = *(const uint4*)g_;                     Pb = *(const uint4*)(g_ + 8); \
    Qa = *(const uint4*)(g_ + dx_ * 64);        Qb = *(const uint4*)(g_ + dx_ * 64 + 8); \
    Ra = *(const uint4*)(g_ + dy_ * (PH * 64)); Rb = *(const uint4*)(g_ + dy_ * (PH * 64) + 8); \
    Sa = *(const uint4*)(g_ + (dy_ * PH + dx_) * 64); Sb = *(const uint4*)(g_ + (dy_ * PH + dx_) * 64 + 8); \
  } while (0)
#define CMB(J, PA,QA,RA,SA, Wab, Wcd, OUT) do { \
    const unsigned* pa_ = (const unsigned*)&PA; const unsigned* qa_ = (const unsigned*)&QA; \
    const unsigned* ra_ = (const unsigned*)&RA; const unsigned* sa_ = (const unsigned*)&SA; \
    float lo_ = Wab.x * bflo(pa_[J]) + Wab.y * bflo(qa_[J]) + Wcd.x * bflo(ra_[J]) + Wcd.y * bflo(sa_[J]); \
    float hi_ = Wab.x * bfhi(pa_[J]) + Wab.y * bfhi(qa_[J]) + Wcd.x * bfhi(ra_[J]) + Wcd.y * bfhi(sa_[J]); \
    OUT = (unsigned)f2bf(lo_) | ((unsigned)f2bf(hi_) << 16); \
  } while (0)
#define CSTORE_R(BUFOFF, Pa,Pb,Qa,Qb,Ra,Rb,Sa,Sb, Wab, Wcd) do { \
    unsigned oa_[4], ob_[4]; \
    CMB(0, Pa,Qa,Ra,Sa, Wab, Wcd, oa_[0]); CMB(1, Pa,Qa,Ra,Sa, Wab, Wcd, oa_[1]); \
    CMB(2, Pa,Qa,Ra,Sa, Wab, Wcd, oa_[2]); CMB(3, Pa,Qa,Ra,Sa, Wab, Wcd, oa_[3]); \
    CMB(0, Pb,Qb,Rb,Sb, Wab, Wcd, ob_[0]); CMB(1, Pb,Qb,Rb,Sb, Wab, Wcd, ob_[1]); \
    CMB(2, Pb,Qb,Rb,Sb, Wab, Wcd, ob_[2]); CMB(3, Pb,Qb,Rb,Sb, Wab, Wcd, ob_[3]); \
    char* dst_ = (char*)sA + (BUFOFF) + spix * 128; \
    *(uint4*)(dst_ + ((((lg * 2) ^ (spix & 7))) << 4))     = make_uint4(oa_[0], oa_[1], oa_[2], oa_[3]); \
    *(uint4*)(dst_ + ((((lg * 2 + 1) ^ (spix & 7))) << 4)) = make_uint4(ob_[0], ob_[1], ob_[2], ob_[3]); \
  } while (0)

  ISSUE_R(0, Pa0,Pb0,Qa0,Qb0,Ra0,Rb0,Sa0,Sb0, wab0, wcd0);
  CSTORE_R(0, Pa0,Pb0,Qa0,Qb0,Ra0,Rb0,Sa0,Sb0, wab0, wcd0);
  ISSUE_R(1, Pa0,Pb0,Qa0,Qb0,Ra0,Rb0,Sa0,Sb0, wab0, wcd0);
  ISSUE_R(2, Pa1,Pb1,Qa1,Qb1,Ra1,Rb1,Sa1,Sb1, wab1, wcd1);

  f32x4 acc0 = (f32x4){0.f, 0.f, 0.f, 0.f};
  f32x4 acc1 = (f32x4){0.f, 0.f, 0.f, 0.f};
  f32x4 acc2 = (f32x4){0.f, 0.f, 0.f, 0.f};
  f32x4 acc3 = (f32x4){0.f, 0.f, 0.f, 0.f};
  const short* wrow = wtb + (size_t)(wid * 16 + r16) * 576;
  const char* a0base = (const char*)sA + r16 * 128;
  const char* a1base = (const char*)sA + (r16 + 16) * 128;
  const char* a2base = (const char*)sA + (r16 + 32) * 128;
  const char* a3base = (const char*)sA + (r16 + 48) * 128;

#pragma unroll
  for (int kk = 0; kk < 9; ++kk) {
    const int bo = (kk & 1) * 8192;
    __syncthreads();
#pragma unroll
    for (int s = 0; s < 2; ++s) {
      short8 wf = *(const short8*)(wrow + kk * 64 + s * 32 + q * 8);
      int off = bo + ((s * 64 + q * 16) ^ rsw);
      acc0 = MFMA(wf, *(const short8*)(a0base + off), acc0);
      acc1 = MFMA(wf, *(const short8*)(a1base + off), acc1);
      acc2 = MFMA(wf, *(const short8*)(a2base + off), acc2);
      acc3 = MFMA(wf, *(const short8*)(a3base + off), acc3);
    }
    if (kk < 8) {
      const int nbo = ((kk + 1) & 1) * 8192;
      if ((kk & 1) == 0) {
        CSTORE_R(nbo, Pa0,Pb0,Qa0,Qb0,Ra0,Rb0,Sa0,Sb0, wab0, wcd0);
        if (kk + 3 <= 8) ISSUE_R(kk + 3, Pa0,Pb0,Qa0,Qb0,Ra0,Rb0,Sa0,Sb0, wab0, wcd0);
      } else {
        CSTORE_R(nbo, Pa1,Pb1,Qa1,Qb1,Ra1,Rb1,Sa1,Sb1, wab1, wcd1);
        if (kk + 3 <= 8) ISSUE_R(kk + 3, Pa1,Pb1,Qa1,Qb1,Ra1,Rb1,Sa1,Sb1, wab1, wcd1);
      }
    }
  }

  // epilogue: +out1 residual (64-px blocks never cross rows: 192 = 3*64)
  int h0 = p0 / WSZ, w0 = p0 - h0 * WSZ;
  size_t ro = ((size_t)(h0 + 1) * PH + w0 + 1) * 64;
  const __hip_bfloat16* resid = nb + ro;
  __hip_bfloat16* fp = fin + (size_t)b * PP * 64 + ro;
#pragma unroll
  for (int nf = 0; nf < 4; ++nf) {
    f32x4 av = nf == 0 ? acc0 : nf == 1 ? acc1 : nf == 2 ? acc2 : acc3;
    int pix = r16 + nf * 16;
    int co = wid * 16 + q * 4;
    const unsigned* rr = (const unsigned*)(resid + (size_t)pix * 64 + co);
    unsigned r0 = rr[0], r1 = rr[1];
    float o0 = av[0] + bflo(r0);
    float o1 = av[1] + bfhi(r0);
    float o2 = av[2] + bflo(r1);
    float o3 = av[3] + bfhi(r1);
    uint2 pk2 = make_uint2((unsigned)f2bf(o0) | ((unsigned)f2bf(o1) << 16),
                           (unsigned)f2bf(o2) | ((unsigned)f2bf(o3) << 16));
    *(uint2*)(fp + (size_t)pix * 64 + co) = pk2;
  }
#undef ISSUE_R
#undef CMB
#undef CSTORE_R
}

extern "C" void kernel_launch(void* const* d_in, const int* in_sizes, int n_in,
                              void* d_out, int out_size, void* d_ws, size_t ws_size,
                              hipStream_t stream) {
  (void)in_sizes; (void)n_in; (void)out_size; (void)ws_size;
  const float* x     = (const float*)d_in[0];
  const float* inter = (const float*)d_in[1];
  const float* fea   = (const float*)d_in[2];
  const float* rw1   = (const float*)d_in[3];
  const float* rb1   = (const float*)d_in[4];
  const float* rw2   = (const float*)d_in[5];
  const float* rb2   = (const float*)d_in[6];
  const float* caw1  = (const float*)d_in[7];
  const float* cab1  = (const float*)d_in[8];
  const float* caw2  = (const float*)d_in[9];
  const float* cab2  = (const float*)d_in[10];
  const float* offw  = (const float*)d_in[11];
  const float* offb  = (const float*)d_in[12];
  const float* maskw = (const float*)d_in[13];
  const float* maskb = (const float*)d_in[14];
  const float* dw    = (const float*)d_in[15];
  const float* cw    = (const float*)d_in[16];
  const float* cb    = (const float*)d_in[17];

  char* w = (char*)d_ws;
  const size_t P64 = (size_t)NB * PP * 64 * 2 + 4096;
  const size_t PCAT = (size_t)NB * PP * 128 * 2 + 4096;
  __hip_bfloat16* xn   = (__hip_bfloat16*)(w);
  __hip_bfloat16* r1   = (__hip_bfloat16*)(w + P64);
  __hip_bfloat16* res  = (__hip_bfloat16*)(w + 2 * P64);   // conv2 out; out1 in-place; deform residual/src
  float* omb           = (float*)(w + 3 * P64);            // dedicated offset/mask buffer (15.9 MB < P64)
  __hip_bfloat16* cat  = (__hip_bfloat16*)(w + 4 * P64);
  char* tail = w + 4 * P64 + PCAT;
  short* wt1  = (short*)tail; tail += 73728;
  short* wt2c = (short*)tail; tail += 73728;
  short* wtf  = (short*)tail; tail += 73728;
  short* wtom = (short*)tail; tail += 73728;
  float* obb  = (float*)tail; tail += 128;
  short* wtb  = (short*)tail; tail += 73728;
  float* mean = (float*)tail; tail += 1024;
  __hip_bfloat16* fin = r1;         // overlay: fin reuses r1 slot (r1 dead after conv2)

  zb2_k<<<dim3(194, 4), 256, 0, stream>>>(xn, r1, res, cat);
  wts_k<<<dim3(144, 5), 256, 0, stream>>>(rw1, rw2, cw, offw, maskw, offb, maskb, dw,
                                          wt1, wt2c, wtf, wtom, obb, wtb, mean);
  cvt_k<<<dim3(576, 4, 3), 256, 0, stream>>>(x, inter, fea, xn, cat);

  conv_mfma_k<0, true , false><<<768, 512, 0, stream>>>(xn, wt1, rb1, r1, nullptr, nullptr);
  conv_mfma_k<0, false, true ><<<768, 512, 0, stream>>>(r1, wt2c, rb2, res, nullptr, mean);
  out1_k<<<4608, 256, 0, stream>>>(res, xn, mean, caw1, cab1, caw2, cab2);
  offmask_mfma_k<<<768, 512, 0, stream>>>(cat, wtom, obb, omb);
  deform_mfma_k<<<NB * 576, 256, 0, stream>>>(res, omb, wtb, fin);
  conv_mfma_k<1, false, false><<<768, 512, 0, stream>>>(fin, wtf, cb, nullptr, (float*)d_out, nullptr);
}